// Round 3
// baseline (296.198 us; speedup 1.0000x reference)
//
#include <hip/hip_runtime.h>
#include <math.h>

// Problem constants: B=4, NF=64, H=W=128, K=9
// d_in order: nbr, ref, w1, b1, w2, b2, w3, b3, w_off, b_off, w_dcn, b_dcn
// d_out: feat [4,64,128,128] | offset [4,18,128,128] | mask [4,9,128,128]

typedef _Float16 h8 __attribute__((ext_vector_type(8)));  // 8 f16 (4 VGPRs)
typedef _Float16 h4 __attribute__((ext_vector_type(4)));  // 4 f16 (2 VGPRs)
typedef _Float16 h2 __attribute__((ext_vector_type(2)));  // packed f16 pair
typedef float f4 __attribute__((ext_vector_type(4)));     // 4 fp32 acc

// ================ merged setup: weight prep + border zero + input prep ================
__global__ __launch_bounds__(256) void setup_kernel(
    const float* __restrict__ nbr, const float* __restrict__ refp,
    const float* __restrict__ w1, const float* __restrict__ w2,
    const float* __restrict__ w3, const float* __restrict__ w_off,
    const float* __restrict__ w_dcn,
    _Float16* __restrict__ X1, _Float16* __restrict__ X2,
    _Float16* __restrict__ B64, _Float16* __restrict__ C64,
    _Float16* __restrict__ wF1, _Float16* __restrict__ wF2,
    _Float16* __restrict__ wF3, _Float16* __restrict__ wFo,
    _Float16* __restrict__ wFd) {
  __shared__ float t[64 * 65];
  int bid = blockIdx.x;
  int tid = threadIdx.x;
  if (bid < 792) {
    int i = bid * 256 + tid;
    if (i < 73728) {                       // w1: NCH=4 (128 IC)
      int j = i;
      int icw = j & 31; int t1 = j >> 5; int oc = t1 & 63; int t2 = t1 >> 6;
      int ch = t2 & 3; int tap = t2 >> 2; int ic = ch * 32 + icw;
      wF1[j] = (_Float16)w1[(oc * 128 + ic) * 9 + tap];
    } else if (i < 110592) {               // w2
      int j = i - 73728;
      int icw = j & 31; int t1 = j >> 5; int oc = t1 & 63; int t2 = t1 >> 6;
      int ch = t2 & 1; int tap = t2 >> 1; int ic = ch * 32 + icw;
      wF2[j] = (_Float16)w2[(oc * 64 + ic) * 9 + tap];
    } else if (i < 147456) {               // w3
      int j = i - 110592;
      int icw = j & 31; int t1 = j >> 5; int oc = t1 & 63; int t2 = t1 >> 6;
      int ch = t2 & 1; int tap = t2 >> 1; int ic = ch * 32 + icw;
      wF3[j] = (_Float16)w3[(oc * 64 + ic) * 9 + tap];
    } else if (i < 165888) {               // w_off padded to 32 oc
      int j = i - 147456;
      int icw = j & 31; int t1 = j >> 5; int oc = t1 & 31; int t2 = t1 >> 5;
      int ch = t2 & 1; int tap = t2 >> 1; int ic = ch * 32 + icw;
      float v = (oc < 27) ? w_off[(oc * 64 + ic) * 9 + tap] : 0.f;
      wFo[j] = (_Float16)v;
    } else if (i < 202752) {               // w_dcn -> [oc][tap*64+c]
      int j = i - 165888;
      int oc = j / 576; int r = j - oc * 576; int tap = r >> 6; int c = r & 63;
      wFd[j] = (_Float16)w_dcn[(oc * 64 + c) * 9 + tap];
    }
    return;
  }
  if (bid < 1050) {
    int i = (bid - 792) * 256 + tid;       // 66048 = 4 buf * 4 b * 516 px * 8 chunks
    int bufi = i / 16512;
    int j = i - bufi * 16512;
    int b = j / 4128;
    int r = j - b * 4128;
    int p = r >> 3; int cg = r & 7;
    int row, col;
    if (p < 130)      { row = 0;   col = p; }
    else if (p < 260) { row = 129; col = p - 130; }
    else if (p < 388) { row = 1 + (p - 260); col = 0; }
    else              { row = 1 + (p - 388); col = 129; }
    _Float16* dst = (bufi == 0) ? X1 : (bufi == 1) ? X2 : (bufi == 2) ? B64 : C64;
    uint4 z; z.x = z.y = z.z = z.w = 0u;
    *(uint4*)(dst + ((size_t)(b * 130 + row) * 130 + col) * 64 + cg * 8) = z;
    return;
  }
  // ---- input prep: fp32 NCHW -> padded NHWC f16 (64-px half-rows)
  int j = bid - 1050;                      // 2048 = 2 src * 4 b * 128 y * 2 half
  int half = j & 1;
  int y = (j >> 1) & 127;
  int b = (j >> 8) & 3;
  int src = j >> 10;
  const float* sp = src ? refp : nbr;
  _Float16* dst = src ? X2 : X1;
  for (int l = tid; l < 64 * 64; l += 256) {
    int c = l >> 6, gx = l & 63;
    t[c * 65 + gx] = sp[(((size_t)b * 64 + c) << 14) + (y << 7) + half * 64 + gx];
  }
  __syncthreads();
  unsigned* dstU = (unsigned*)dst;
  for (int l = tid; l < 64 * 32; l += 256) {
    int pxl = l >> 5, c2 = l & 31;
    union { _Float16 h[2]; unsigned u; } pk;
    pk.h[0] = (_Float16)t[(2 * c2) * 65 + pxl];
    pk.h[1] = (_Float16)t[(2 * c2 + 1) * 65 + pxl];
    dstU[((size_t)(b * 130 + y + 1) * 130 + 1 + half * 64 + pxl) * 32 + c2] = pk.u;
  }
}

// ================ w64 conv: wave tile M=64 x N=64, 2 waves/block, 512 blocks x 128 thr.
// (known-good form; w32 M-split regressed: doubled load:MFMA ratio + traffic)
// SPLIT: concat of X1 (c<2) and X2 (c>=2) for conv1.
template <int NCH, bool SPLIT>
__global__ __launch_bounds__(128, 1) void conv3x3_w64_kernel(
    const _Float16* __restrict__ X1, const _Float16* __restrict__ X2,
    const _Float16* __restrict__ W, const float* __restrict__ bias,
    _Float16* __restrict__ outP) {
  int tid = threadIdx.x;
  int wv = tid >> 6, L = tid & 63;
  int lm = L & 15, lq = L >> 4;
  int bid = blockIdx.x;                 // 512 = 8 xcd * 16 ystrip * 4 b
  int xcd = bid & 7, j = bid >> 3;
  int y = (xcd << 4) | (j & 15);
  int b = j >> 4;
  int px0 = wv * 64;

  f4 acc[4][4];
#pragma unroll
  for (int i = 0; i < 4; ++i)
#pragma unroll
    for (int n = 0; n < 4; ++n) acc[i][n] = (f4)0.f;

#pragma unroll
  for (int c = 0; c < NCH; ++c) {
    const _Float16* src = (SPLIT && c >= 2) ? X2 : X1;
    int cl = SPLIT ? (c & 1) : c;
#pragma unroll
    for (int tap = 0; tap < 9; ++tap) {
      const int dy = tap / 3 - 1, dx = tap % 3 - 1;
      const _Float16* xb = src + ((size_t)((b * 130 + (y + 1 + dy)) * 130) + (1 + dx) + px0) * 64
                               + cl * 32 + lq * 8;
      h8 b0 = *(const h8*)(xb + lm * 64);
      h8 b1 = *(const h8*)(xb + (16 + lm) * 64);
      h8 b2 = *(const h8*)(xb + (32 + lm) * 64);
      h8 b3 = *(const h8*)(xb + (48 + lm) * 64);
      const _Float16* wp = W + (size_t)((tap * NCH + c) * 64) * 32 + lm * 32 + lq * 8;
      h8 a0 = *(const h8*)(wp);
      h8 a1 = *(const h8*)(wp + 512);
      h8 a2 = *(const h8*)(wp + 1024);
      h8 a3 = *(const h8*)(wp + 1536);
#pragma unroll
      for (int mt = 0; mt < 4; ++mt) {
        h8 am = (mt == 0) ? a0 : (mt == 1) ? a1 : (mt == 2) ? a2 : a3;
        acc[mt][0] = __builtin_amdgcn_mfma_f32_16x16x32_f16(am, b0, acc[mt][0], 0, 0, 0);
        acc[mt][1] = __builtin_amdgcn_mfma_f32_16x16x32_f16(am, b1, acc[mt][1], 0, 0, 0);
        acc[mt][2] = __builtin_amdgcn_mfma_f32_16x16x32_f16(am, b2, acc[mt][2], 0, 0, 0);
        acc[mt][3] = __builtin_amdgcn_mfma_f32_16x16x32_f16(am, b3, acc[mt][3], 0, 0, 0);
      }
    }
  }
  const size_t obase = ((size_t)(b * 130 + (y + 1)) * 130 + 1) * 64;
#pragma unroll
  for (int mt = 0; mt < 4; ++mt)
#pragma unroll
    for (int nt = 0; nt < 4; ++nt) {
      int px = px0 + nt * 16 + lm;
      h4 pk;
#pragma unroll
      for (int r = 0; r < 4; ++r) {
        int oc = mt * 16 + lq * 4 + r;
        float v = acc[mt][nt][r] + bias[oc];
        v = (v >= 0.f) ? v : 0.1f * v;
        pk[r] = (_Float16)v;
      }
      *(h4*)(outP + obase + (size_t)px * 64 + mt * 16 + lq * 4) = pk;
    }
}

// ================ FUSED conv_off + DCN, barrier-free, oc-split wave pairs.
// dur*occ analysis (r0-r2): barrier-free structure has lowest per-wave cost but was
// capped at 4096 waves (50% occ). Split phase-2 oc across wave PAIRS: 16px x 32oc
// per wave -> 8192 waves = 2048 blocks * 4 waves; (256,8) + VGPR<=64 + 7KB LDS ->
// 8 blocks/CU = 32 waves/CU target. Phase 1 (conv_off) duplicated in both waves of
// a pair (keeps waves independent: no barrier, no cross-wave Soff); only the
// oc-half-0 wave writes off/mask to global. Lane (lm,lq) gathers px=lm, ch
// s*32+lq*8 = exact 16x16x32 B-fragment; samples feed MFMA directly (no staging).
__global__ __launch_bounds__(256, 8) void off_dcn_kernel(
    const _Float16* __restrict__ Xc, const _Float16* __restrict__ Xs,
    const _Float16* __restrict__ Wo, const float* __restrict__ bo,
    const _Float16* __restrict__ wD, const float* __restrict__ bd,
    float* __restrict__ off_out, float* __restrict__ mask_out,
    float* __restrict__ out) {
  __shared__ float Soff[4][16][28];     // per-WAVE slice: [px][0..17]=off, [18..26]=mask
  int tid = threadIdx.x;
  int wv = tid >> 6, L = tid & 63;
  int lm = L & 15, lq = L >> 4;
  int lq8 = lq * 8;
  int wpx = wv >> 1;                    // px-tile within block (0/1)
  int wM = wv & 1;                      // oc half (0/1)
  int g = blockIdx.x;                   // 2048 = 8 xcd * (4 q * 16 ystrip * 4 b)
  int xcd = g & 7;
  int r0 = g >> 3;
  int q = r0 & 3;
  int y = (xcd << 4) | ((r0 >> 2) & 15);
  int b = r0 >> 6;
  int px0 = q * 32 + wpx * 16;          // wave's 16-px tile base
  int gpx = px0 + lm;                   // this lane's pixel
  int hw = (y << 7) + gpx;
  int rb = b * 130;

  // ---- phase 1: conv_off (32 oc x 16 px) for this wave's pixels (dup per oc-pair)
  {
    f4 oa[2];
    oa[0] = (f4)0.f; oa[1] = (f4)0.f;
#pragma unroll
    for (int c = 0; c < 2; ++c)
#pragma unroll
      for (int tap = 0; tap < 9; ++tap) {
        const int dy = tap / 3 - 1, dx = tap % 3 - 1;
        const _Float16* xb = Xc + ((size_t)((rb + (y + 1 + dy)) * 130) + (1 + dx) + px0) * 64
                                + c * 32 + lq8;
        h8 b0 = *(const h8*)(xb + lm * 64);
        const _Float16* wp = Wo + (size_t)((tap * 2 + c) * 32 + lm) * 32 + lq8;
        h8 a0 = *(const h8*)(wp);
        h8 a1 = *(const h8*)(wp + 512);
        oa[0] = __builtin_amdgcn_mfma_f32_16x16x32_f16(a0, b0, oa[0], 0, 0, 0);
        oa[1] = __builtin_amdgcn_mfma_f32_16x16x32_f16(a1, b0, oa[1], 0, 0, 0);
      }
#pragma unroll
    for (int mt = 0; mt < 2; ++mt)
#pragma unroll
      for (int r = 0; r < 4; ++r) {
        int oc = mt * 16 + lq * 4 + r;
        if (oc < 18) {
          float v = 15.f * tanhf(oa[mt][r] + bo[oc]);
          Soff[wv][lm][oc] = v;
          if (wM == 0) off_out[((b * 18 + oc) << 14) + hw] = v;
        } else if (oc < 27) {
          float v = 1.f / (1.f + expf(-(oa[mt][r] + bo[oc])));
          Soff[wv][lm][oc] = v;
          if (wM == 0) mask_out[((b * 9 + (oc - 18)) << 14) + hw] = v;
        }
      }
  }
  // no __syncthreads: Soff slice is written and read by the SAME wave;
  // compiler orders the ds_write -> ds_read via lgkmcnt.

  // ---- phase 2: DCN (32 oc half), 9 taps, gather straight into B-fragments
  f4 acc[2];
  acc[0] = (f4)0.f; acc[1] = (f4)0.f;

#pragma unroll
  for (int k = 0; k < 9; ++k) {
    const int kr = k / 3, kc = k - kr * 3;
    float oy = Soff[wv][lm][2 * k];
    float ox = Soff[wv][lm][2 * k + 1];
    float m = Soff[wv][lm][18 + k];
    float py = (float)(y + kr - 1) + oy;
    float pxf = (float)(gpx + kc - 1) + ox;
    float fy = floorf(py), fx = floorf(pxf);
    float wy = py - fy, wx = pxf - fx;
    int y0 = (int)fy, x0 = (int)fx;
    int y1 = y0 + 1, x1 = x0 + 1;
    float vy0 = ((unsigned)y0 < 128u) ? 1.f : 0.f;
    float vy1 = ((unsigned)y1 < 128u) ? 1.f : 0.f;
    float vx0 = ((unsigned)x0 < 128u) ? 1.f : 0.f;
    float vx1 = ((unsigned)x1 < 128u) ? 1.f : 0.f;
    float ey = 1.f - wy, ex = 1.f - wx;
    _Float16 w00 = (_Float16)(ey * ex * m * vy0 * vx0);
    _Float16 w01 = (_Float16)(ey * wx * m * vy0 * vx1);
    _Float16 w10 = (_Float16)(wy * ex * m * vy1 * vx0);
    _Float16 w11 = (_Float16)(wy * wx * m * vy1 * vx1);
    h2 W00 = {w00, w00}, W01 = {w01, w01}, W10 = {w10, w10}, W11 = {w11, w11};
    int y0c = min(max(y0, 0), 127) + 1, y1c = min(max(y1, 0), 127) + 1;
    int x0c = min(max(x0, 0), 127) + 1, x1c = min(max(x1, 0), 127) + 1;
    const _Float16* r0p = Xs + (((size_t)((rb + y0c) * 130)) << 6);
    const _Float16* r1p = Xs + (((size_t)((rb + y1c) * 130)) << 6);
    int c0 = x0c << 6, c1 = x1c << 6;
#pragma unroll
    for (int s = 0; s < 2; ++s) {
      int cb = s * 32 + lq8;            // B-frag channel base: k=(lane>>4)*8 of slice s
      h8 v00 = *(const h8*)(r0p + c0 + cb);
      h8 v01 = *(const h8*)(r0p + c1 + cb);
      h8 v10 = *(const h8*)(r1p + c0 + cb);
      h8 v11 = *(const h8*)(r1p + c1 + cb);
      h8 bv;
#pragma unroll
      for (int j2 = 0; j2 < 4; ++j2) {
        h2 a  = {v00[2 * j2], v00[2 * j2 + 1]};
        h2 bb = {v01[2 * j2], v01[2 * j2 + 1]};
        h2 cc = {v10[2 * j2], v10[2 * j2 + 1]};
        h2 dd = {v11[2 * j2], v11[2 * j2 + 1]};
        h2 r = a * W00;
        r += bb * W01;
        r += cc * W10;
        r += dd * W11;
        bv[2 * j2] = r[0];
        bv[2 * j2 + 1] = r[1];
      }
      const _Float16* wp = wD + (size_t)(wM * 32 + lm) * 576 + k * 64 + cb;
      acc[0] = __builtin_amdgcn_mfma_f32_16x16x32_f16(*(const h8*)(wp), bv, acc[0], 0, 0, 0);
      acc[1] = __builtin_amdgcn_mfma_f32_16x16x32_f16(*(const h8*)(wp + 16 * 576), bv, acc[1], 0, 0, 0);
    }
  }

  // epilogue: bias + lrelu, fp32 NCHW (this wave's 32-oc half)
#pragma unroll
  for (int m = 0; m < 2; ++m)
#pragma unroll
    for (int r = 0; r < 4; ++r) {
      int oc = wM * 32 + m * 16 + lq * 4 + r;
      float v = acc[m][r] + bd[oc];
      v = (v >= 0.f) ? v : 0.1f * v;
      out[(((b << 6) + oc) << 14) + (y << 7) + gpx] = v;
    }
}

extern "C" void kernel_launch(void* const* d_in, const int* in_sizes, int n_in,
                              void* d_out, int out_size, void* d_ws, size_t ws_size,
                              hipStream_t stream) {
  const float* nbr   = (const float*)d_in[0];
  const float* refp  = (const float*)d_in[1];
  const float* w1    = (const float*)d_in[2];
  const float* b1    = (const float*)d_in[3];
  const float* w2    = (const float*)d_in[4];
  const float* b2    = (const float*)d_in[5];
  const float* w3    = (const float*)d_in[6];
  const float* b3    = (const float*)d_in[7];
  const float* w_off = (const float*)d_in[8];
  const float* b_off = (const float*)d_in[9];
  const float* w_dcn = (const float*)d_in[10];
  const float* b_dcn = (const float*)d_in[11];

  float* outp = (float*)d_out;
  float* feat = outp;                       // 4*64*16384
  float* offp = outp + 4194304;             // 4*18*16384
  float* mskp = outp + 4194304 + 1179648;   // 4*9*16384

  // ws layout: four padded NHWC f16 buffers [4][130][130][64] + f16 weights (~33.4 MiB)
  char* ws = (char*)d_ws;
  const size_t PB = 8652800;                // bytes per padded buffer
  _Float16* X1  = (_Float16*)ws;            // nbr padded (conv1 in + DCN sample src)
  _Float16* X2  = (_Float16*)(ws + PB);     // ref padded
  _Float16* B64 = (_Float16*)(ws + 2 * PB); // conv1 out / conv3 out
  _Float16* C64 = (_Float16*)(ws + 3 * PB); // conv2 out
  char* p = ws + 4 * PB;
  _Float16* wF1 = (_Float16*)p;  p += (size_t)73728 * 2;
  _Float16* wF2 = (_Float16*)p;  p += (size_t)36864 * 2;
  _Float16* wF3 = (_Float16*)p;  p += (size_t)36864 * 2;
  _Float16* wFo = (_Float16*)p;  p += (size_t)18432 * 2;
  _Float16* wFd = (_Float16*)p;

  // 5 dispatches total
  setup_kernel<<<dim3(3098), 256, 0, stream>>>(nbr, refp, w1, w2, w3, w_off, w_dcn,
                                               X1, X2, B64, C64, wF1, wF2, wF3, wFo, wFd);
  conv3x3_w64_kernel<4, true><<<dim3(512), 128, 0, stream>>>(X1, X2, wF1, b1, B64);
  conv3x3_w64_kernel<2, false><<<dim3(512), 128, 0, stream>>>(B64, nullptr, wF2, b2, C64);
  conv3x3_w64_kernel<2, false><<<dim3(512), 128, 0, stream>>>(C64, nullptr, wF3, b3, B64);
  off_dcn_kernel<<<dim3(2048), 256, 0, stream>>>(B64, X1, wFo, b_off, wFd, b_dcn,
                                                 offp, mskp, feat);
}

// Round 4
// 229.084 us; speedup vs baseline: 1.2930x; 1.2930x over previous
//
#include <hip/hip_runtime.h>
#include <math.h>

// Problem constants: B=4, NF=64, H=W=128, K=9
// d_in order: nbr, ref, w1, b1, w2, b2, w3, b3, w_off, b_off, w_dcn, b_dcn
// d_out: feat [4,64,128,128] | offset [4,18,128,128] | mask [4,9,128,128]

typedef _Float16 h8 __attribute__((ext_vector_type(8)));  // 8 f16 (4 VGPRs)
typedef _Float16 h4 __attribute__((ext_vector_type(4)));  // 4 f16 (2 VGPRs)
typedef _Float16 h2 __attribute__((ext_vector_type(2)));  // packed f16 pair
typedef float f4 __attribute__((ext_vector_type(4)));     // 4 fp32 acc

// ================ merged setup: weight prep + border zero + input prep ================
__global__ __launch_bounds__(256) void setup_kernel(
    const float* __restrict__ nbr, const float* __restrict__ refp,
    const float* __restrict__ w1, const float* __restrict__ w2,
    const float* __restrict__ w3, const float* __restrict__ w_off,
    const float* __restrict__ w_dcn,
    _Float16* __restrict__ X1, _Float16* __restrict__ X2,
    _Float16* __restrict__ B64, _Float16* __restrict__ C64,
    _Float16* __restrict__ wF1, _Float16* __restrict__ wF2,
    _Float16* __restrict__ wF3, _Float16* __restrict__ wFo,
    _Float16* __restrict__ wFd) {
  __shared__ float t[64 * 65];
  int bid = blockIdx.x;
  int tid = threadIdx.x;
  if (bid < 792) {
    int i = bid * 256 + tid;
    if (i < 73728) {                       // w1: NCH=4 (128 IC)
      int j = i;
      int icw = j & 31; int t1 = j >> 5; int oc = t1 & 63; int t2 = t1 >> 6;
      int ch = t2 & 3; int tap = t2 >> 2; int ic = ch * 32 + icw;
      wF1[j] = (_Float16)w1[(oc * 128 + ic) * 9 + tap];
    } else if (i < 110592) {               // w2
      int j = i - 73728;
      int icw = j & 31; int t1 = j >> 5; int oc = t1 & 63; int t2 = t1 >> 6;
      int ch = t2 & 1; int tap = t2 >> 1; int ic = ch * 32 + icw;
      wF2[j] = (_Float16)w2[(oc * 64 + ic) * 9 + tap];
    } else if (i < 147456) {               // w3
      int j = i - 110592;
      int icw = j & 31; int t1 = j >> 5; int oc = t1 & 63; int t2 = t1 >> 6;
      int ch = t2 & 1; int tap = t2 >> 1; int ic = ch * 32 + icw;
      wF3[j] = (_Float16)w3[(oc * 64 + ic) * 9 + tap];
    } else if (i < 165888) {               // w_off -> A-frag contiguous [tap*2+c][mt][lane][8]
      int jj = i - 147456;                 // 18432 = 18 * 1024
      int pc = jj >> 10;                   // tap*2+c
      int mt = (jj >> 9) & 1;
      int Lx = (jj >> 3) & 63;
      int e  = jj & 7;
      int tap = pc >> 1, c = pc & 1;
      int oc = mt * 16 + (Lx & 15);
      int ic = c * 32 + (Lx >> 4) * 8 + e;
      float v = (oc < 27) ? w_off[(oc * 64 + ic) * 9 + tap] : 0.f;
      wFo[jj] = (_Float16)v;
    } else if (i < 202752) {               // w_dcn -> A-frag contiguous [k*2+s][mt 4][lane][8]
      int jj = i - 165888;                 // 36864 = 18 * 2048
      int ks = jj >> 11;                   // k*2+s
      int mt = (jj >> 9) & 3;
      int Lx = (jj >> 3) & 63;
      int e  = jj & 7;
      int k = ks >> 1, s = ks & 1;
      int oc = mt * 16 + (Lx & 15);
      int ch = s * 32 + (Lx >> 4) * 8 + e;
      wFd[jj] = (_Float16)w_dcn[(oc * 64 + ch) * 9 + k];
    }
    return;
  }
  if (bid < 1050) {
    int i = (bid - 792) * 256 + tid;       // 66048 = 4 buf * 4 b * 516 px * 8 chunks
    int bufi = i / 16512;
    int j = i - bufi * 16512;
    int b = j / 4128;
    int r = j - b * 4128;
    int p = r >> 3; int cg = r & 7;
    int row, col;
    if (p < 130)      { row = 0;   col = p; }
    else if (p < 260) { row = 129; col = p - 130; }
    else if (p < 388) { row = 1 + (p - 260); col = 0; }
    else              { row = 1 + (p - 388); col = 129; }
    _Float16* dst = (bufi == 0) ? X1 : (bufi == 1) ? X2 : (bufi == 2) ? B64 : C64;
    uint4 z; z.x = z.y = z.z = z.w = 0u;
    *(uint4*)(dst + ((size_t)(b * 130 + row) * 130 + col) * 64 + cg * 8) = z;
    return;
  }
  // ---- input prep: fp32 NCHW -> padded NHWC f16 (64-px half-rows)
  int j = bid - 1050;                      // 2048 = 2 src * 4 b * 128 y * 2 half
  int half = j & 1;
  int y = (j >> 1) & 127;
  int b = (j >> 8) & 3;
  int src = j >> 10;
  const float* sp = src ? refp : nbr;
  _Float16* dst = src ? X2 : X1;
  for (int l = tid; l < 64 * 64; l += 256) {
    int c = l >> 6, gx = l & 63;
    t[c * 65 + gx] = sp[(((size_t)b * 64 + c) << 14) + (y << 7) + half * 64 + gx];
  }
  __syncthreads();
  unsigned* dstU = (unsigned*)dst;
  for (int l = tid; l < 64 * 32; l += 256) {
    int pxl = l >> 5, c2 = l & 31;
    union { _Float16 h[2]; unsigned u; } pk;
    pk.h[0] = (_Float16)t[(2 * c2) * 65 + pxl];
    pk.h[1] = (_Float16)t[(2 * c2 + 1) * 65 + pxl];
    dstU[((size_t)(b * 130 + y + 1) * 130 + 1 + half * 64 + pxl) * 32 + c2] = pk.u;
  }
}

// ================ K-split conv: tile M=64 oc x N=64 px, TWO waves per tile splitting
// input channels; 256-thr blocks (2 tiles), 512 blocks -> 2048 waves = 2 waves/SIMD
// (old form was 1 wave/SIMD, fully latency-exposed). Per-wave loads halve, total
// traffic unchanged (unlike the failed r1 M-split). 32KB LDS pair-reduction + 1 barrier.
// SPLIT: conv1 concat; kw=0 -> X1 (c 0,1), kw=1 -> X2 (c 2,3).
template <int NCH, bool SPLIT>
__global__ __launch_bounds__(256, 2) void conv3x3_ks_kernel(
    const _Float16* __restrict__ X1, const _Float16* __restrict__ X2,
    const _Float16* __restrict__ W, const float* __restrict__ bias,
    _Float16* __restrict__ outP) {
  __shared__ f4 Lred[2][16][64];        // 32 KB: [pair][acc frag][lane]
  int tid = threadIdx.x;
  int wv = tid >> 6, L = tid & 63;
  int lm = L & 15, lq = L >> 4;
  int pr = wv >> 1;                     // pair = px half
  int kw = wv & 1;                      // k-split index
  int bid = blockIdx.x;                 // 512 = 8 xcd * 16 ystrip * 4 b
  int xcd = bid & 7, j = bid >> 3;
  int y = (xcd << 4) | (j & 15);
  int b = j >> 4;
  int px0 = pr * 64;

  f4 acc[4][4];
#pragma unroll
  for (int i = 0; i < 4; ++i)
#pragma unroll
    for (int n = 0; n < 4; ++n) acc[i][n] = (f4)0.f;

#pragma unroll
  for (int ci = 0; ci < NCH / 2; ++ci) {
    int c = kw * (NCH / 2) + ci;
    const _Float16* src = (SPLIT && c >= 2) ? X2 : X1;
    int cl = SPLIT ? (c & 1) : c;
#pragma unroll
    for (int tap = 0; tap < 9; ++tap) {
      const int dy = tap / 3 - 1, dx = tap % 3 - 1;
      const _Float16* xb = src + ((size_t)((b * 130 + (y + 1 + dy)) * 130) + (1 + dx) + px0) * 64
                               + cl * 32 + lq * 8;
      h8 b0 = *(const h8*)(xb + lm * 64);
      h8 b1 = *(const h8*)(xb + (16 + lm) * 64);
      h8 b2 = *(const h8*)(xb + (32 + lm) * 64);
      h8 b3 = *(const h8*)(xb + (48 + lm) * 64);
      const _Float16* wp = W + (size_t)((tap * NCH + c) * 64) * 32 + lm * 32 + lq * 8;
      h8 a0 = *(const h8*)(wp);
      h8 a1 = *(const h8*)(wp + 512);
      h8 a2 = *(const h8*)(wp + 1024);
      h8 a3 = *(const h8*)(wp + 1536);
#pragma unroll
      for (int mt = 0; mt < 4; ++mt) {
        h8 am = (mt == 0) ? a0 : (mt == 1) ? a1 : (mt == 2) ? a2 : a3;
        acc[mt][0] = __builtin_amdgcn_mfma_f32_16x16x32_f16(am, b0, acc[mt][0], 0, 0, 0);
        acc[mt][1] = __builtin_amdgcn_mfma_f32_16x16x32_f16(am, b1, acc[mt][1], 0, 0, 0);
        acc[mt][2] = __builtin_amdgcn_mfma_f32_16x16x32_f16(am, b2, acc[mt][2], 0, 0, 0);
        acc[mt][3] = __builtin_amdgcn_mfma_f32_16x16x32_f16(am, b3, acc[mt][3], 0, 0, 0);
      }
    }
  }
  // pair reduction: kw=1 dumps partials, kw=0 adds + stores
  if (kw) {
#pragma unroll
    for (int mt = 0; mt < 4; ++mt)
#pragma unroll
      for (int nt = 0; nt < 4; ++nt)
        Lred[pr][mt * 4 + nt][L] = acc[mt][nt];
  }
  __syncthreads();
  if (kw == 0) {
#pragma unroll
    for (int mt = 0; mt < 4; ++mt)
#pragma unroll
      for (int nt = 0; nt < 4; ++nt)
        acc[mt][nt] += Lred[pr][mt * 4 + nt][L];
    const size_t obase = ((size_t)(b * 130 + (y + 1)) * 130 + 1) * 64;
#pragma unroll
    for (int mt = 0; mt < 4; ++mt)
#pragma unroll
      for (int nt = 0; nt < 4; ++nt) {
        int px = px0 + nt * 16 + lm;
        h4 pk;
#pragma unroll
        for (int r = 0; r < 4; ++r) {
          int oc = mt * 16 + lq * 4 + r;
          float v = acc[mt][nt][r] + bias[oc];
          v = (v >= 0.f) ? v : 0.1f * v;
          pk[r] = (_Float16)v;
        }
        *(h4*)(outP + obase + (size_t)px * 64 + mt * 16 + lq * 4) = pk;
      }
  }
}

// ================ FUSED conv_off + DCN, barrier-free + explicit MLP batching.
// r2 tiling (16px x 64oc per wave, 1024 blocks, (256,4) -> VGPR<=128, 16 waves/CU).
// MLP fixes vs r2 (which had ~4 loads in flight/wave):
//  - gathers issued in explicit batches of 12 (3 taps x 4 corners, h8 gv[12] static)
//  - per-group Soff values pulled to registers first (address math off LDS critical path)
//  - wFo/wFd re-laid-out A-fragment-contiguous: weight loads are coalesced 1KB/wave
//    (were 16 scattered 64B segments each)
__global__ __launch_bounds__(256, 4) void off_dcn_kernel(
    const _Float16* __restrict__ Xc, const _Float16* __restrict__ Xs,
    const _Float16* __restrict__ Wo, const float* __restrict__ bo,
    const _Float16* __restrict__ wD, const float* __restrict__ bd,
    float* __restrict__ off_out, float* __restrict__ mask_out,
    float* __restrict__ out) {
  __shared__ float Soff[4][16][28];     // per-WAVE slice: [px][0..17]=off, [18..26]=mask
  int tid = threadIdx.x;
  int wv = tid >> 6, L = tid & 63;
  int lm = L & 15, lq = L >> 4;
  int lq8 = lq * 8;
  int g = blockIdx.x;                   // 1024 = 8 xcd * (2 half * 16 ystrip * 4 b)
  int xcd = g & 7;
  int r0 = g >> 3;
  int half = r0 & 1;
  int y = (xcd << 4) | ((r0 >> 1) & 15);
  int b = r0 >> 5;
  int px0 = half * 64 + wv * 16;        // wave's 16-px tile base
  int gpx = px0 + lm;                   // this lane's pixel
  int hw = (y << 7) + gpx;
  int rb = b * 130;

  // ---- phase 1: conv_off (32 oc x 16 px) for this wave's pixels
  {
    f4 oa[2];
    oa[0] = (f4)0.f; oa[1] = (f4)0.f;
#pragma unroll
    for (int c = 0; c < 2; ++c)
#pragma unroll
      for (int tap = 0; tap < 9; ++tap) {
        const int dy = tap / 3 - 1, dx = tap % 3 - 1;
        const _Float16* xb = Xc + ((size_t)((rb + (y + 1 + dy)) * 130) + (1 + dx) + px0) * 64
                                + c * 32 + lq8;
        h8 b0 = *(const h8*)(xb + lm * 64);
        const _Float16* wp = Wo + (size_t)(tap * 2 + c) * 1024 + L * 8;
        h8 a0 = *(const h8*)(wp);
        h8 a1 = *(const h8*)(wp + 512);
        oa[0] = __builtin_amdgcn_mfma_f32_16x16x32_f16(a0, b0, oa[0], 0, 0, 0);
        oa[1] = __builtin_amdgcn_mfma_f32_16x16x32_f16(a1, b0, oa[1], 0, 0, 0);
      }
#pragma unroll
    for (int mt = 0; mt < 2; ++mt)
#pragma unroll
      for (int r = 0; r < 4; ++r) {
        int oc = mt * 16 + lq * 4 + r;
        if (oc < 18) {
          float v = 15.f * tanhf(oa[mt][r] + bo[oc]);
          off_out[((b * 18 + oc) << 14) + hw] = v;
          Soff[wv][lm][oc] = v;
        } else if (oc < 27) {
          float v = 1.f / (1.f + expf(-(oa[mt][r] + bo[oc])));
          mask_out[((b * 9 + (oc - 18)) << 14) + hw] = v;
          Soff[wv][lm][oc] = v;
        }
      }
  }
  // no __syncthreads: Soff slice is written and read by the SAME wave (lgkmcnt order).

  // ---- phase 2: DCN, 3 groups of 3 taps, 12-gather batches
  f4 acc[4];
#pragma unroll
  for (int mm = 0; mm < 4; ++mm) acc[mm] = (f4)0.f;

  const char* Xb = (const char*)Xs;
  const int cbL = lq8 * 2;              // lane channel byte offset within pixel block

#pragma unroll
  for (int gp = 0; gp < 3; ++gp) {
    // --- per-group params into registers (static idx after unroll)
    float soy[3], sox[3], som[3];
#pragma unroll
    for (int t = 0; t < 3; ++t) {
      const int k = gp * 3 + t;
      soy[t] = Soff[wv][lm][2 * k];
      sox[t] = Soff[wv][lm][2 * k + 1];
      som[t] = Soff[wv][lm][18 + k];
    }
    int ro0[3], ro1[3], co0[3], co1[3];
    h2 Wc00[3], Wc01[3], Wc10[3], Wc11[3];
#pragma unroll
    for (int t = 0; t < 3; ++t) {
      const int k = gp * 3 + t;
      const int kr = k / 3, kc = k - kr * 3;
      float py = (float)(y + kr - 1) + soy[t];
      float pxf = (float)(gpx + kc - 1) + sox[t];
      float fy = floorf(py), fx = floorf(pxf);
      float wy = py - fy, wx = pxf - fx;
      int y0 = (int)fy, x0 = (int)fx;
      int y1 = y0 + 1, x1 = x0 + 1;
      float vy0 = ((unsigned)y0 < 128u) ? 1.f : 0.f;
      float vy1 = ((unsigned)y1 < 128u) ? 1.f : 0.f;
      float vx0 = ((unsigned)x0 < 128u) ? 1.f : 0.f;
      float vx1 = ((unsigned)x1 < 128u) ? 1.f : 0.f;
      float ey = 1.f - wy, ex = 1.f - wx;
      float mk = som[t];
      _Float16 w00 = (_Float16)(ey * ex * mk * vy0 * vx0);
      _Float16 w01 = (_Float16)(ey * wx * mk * vy0 * vx1);
      _Float16 w10 = (_Float16)(wy * ex * mk * vy1 * vx0);
      _Float16 w11 = (_Float16)(wy * wx * mk * vy1 * vx1);
      Wc00[t] = (h2){w00, w00}; Wc01[t] = (h2){w01, w01};
      Wc10[t] = (h2){w10, w10}; Wc11[t] = (h2){w11, w11};
      int y0c = min(max(y0, 0), 127) + 1, y1c = min(max(y1, 0), 127) + 1;
      int x0c = min(max(x0, 0), 127) + 1, x1c = min(max(x1, 0), 127) + 1;
      ro0[t] = (rb + y0c) * 16640;      // 130 px * 128 B per row
      ro1[t] = (rb + y1c) * 16640;
      co0[t] = x0c * 128;
      co1[t] = x1c * 128;
    }
    // --- per channel-slice: batch-issue all 12 gathers, then combine+MFMA per tap
#pragma unroll
    for (int s = 0; s < 2; ++s) {
      const int cb2 = cbL + s * 64;
      h8 gv[12];
#pragma unroll
      for (int t = 0; t < 3; ++t) {
        gv[t * 4 + 0] = *(const h8*)(Xb + (ro0[t] + co0[t] + cb2));
        gv[t * 4 + 1] = *(const h8*)(Xb + (ro0[t] + co1[t] + cb2));
        gv[t * 4 + 2] = *(const h8*)(Xb + (ro1[t] + co0[t] + cb2));
        gv[t * 4 + 3] = *(const h8*)(Xb + (ro1[t] + co1[t] + cb2));
      }
#pragma unroll
      for (int t = 0; t < 3; ++t) {
        const int k = gp * 3 + t;
        h8 bv;
#pragma unroll
        for (int j2 = 0; j2 < 4; ++j2) {
          h2 a  = {gv[t * 4 + 0][2 * j2], gv[t * 4 + 0][2 * j2 + 1]};
          h2 bb = {gv[t * 4 + 1][2 * j2], gv[t * 4 + 1][2 * j2 + 1]};
          h2 cc = {gv[t * 4 + 2][2 * j2], gv[t * 4 + 2][2 * j2 + 1]};
          h2 dd = {gv[t * 4 + 3][2 * j2], gv[t * 4 + 3][2 * j2 + 1]};
          h2 r = a * Wc00[t];
          r += bb * Wc01[t];
          r += cc * Wc10[t];
          r += dd * Wc11[t];
          bv[2 * j2] = r[0];
          bv[2 * j2 + 1] = r[1];
        }
        const _Float16* wp = wD + (size_t)(k * 2 + s) * 2048 + L * 8;
        acc[0] = __builtin_amdgcn_mfma_f32_16x16x32_f16(*(const h8*)(wp), bv, acc[0], 0, 0, 0);
        acc[1] = __builtin_amdgcn_mfma_f32_16x16x32_f16(*(const h8*)(wp + 512), bv, acc[1], 0, 0, 0);
        acc[2] = __builtin_amdgcn_mfma_f32_16x16x32_f16(*(const h8*)(wp + 1024), bv, acc[2], 0, 0, 0);
        acc[3] = __builtin_amdgcn_mfma_f32_16x16x32_f16(*(const h8*)(wp + 1536), bv, acc[3], 0, 0, 0);
      }
    }
  }

  // epilogue: bias + lrelu, fp32 NCHW
#pragma unroll
  for (int mt = 0; mt < 4; ++mt)
#pragma unroll
    for (int r = 0; r < 4; ++r) {
      int oc = mt * 16 + lq * 4 + r;
      float v = acc[mt][r] + bd[oc];
      v = (v >= 0.f) ? v : 0.1f * v;
      out[(((b << 6) + oc) << 14) + (y << 7) + gpx] = v;
    }
}

extern "C" void kernel_launch(void* const* d_in, const int* in_sizes, int n_in,
                              void* d_out, int out_size, void* d_ws, size_t ws_size,
                              hipStream_t stream) {
  const float* nbr   = (const float*)d_in[0];
  const float* refp  = (const float*)d_in[1];
  const float* w1    = (const float*)d_in[2];
  const float* b1    = (const float*)d_in[3];
  const float* w2    = (const float*)d_in[4];
  const float* b2    = (const float*)d_in[5];
  const float* w3    = (const float*)d_in[6];
  const float* b3    = (const float*)d_in[7];
  const float* w_off = (const float*)d_in[8];
  const float* b_off = (const float*)d_in[9];
  const float* w_dcn = (const float*)d_in[10];
  const float* b_dcn = (const float*)d_in[11];

  float* outp = (float*)d_out;
  float* feat = outp;                       // 4*64*16384
  float* offp = outp + 4194304;             // 4*18*16384
  float* mskp = outp + 4194304 + 1179648;   // 4*9*16384

  // ws layout: four padded NHWC f16 buffers [4][130][130][64] + f16 weights (~33.4 MiB)
  char* ws = (char*)d_ws;
  const size_t PB = 8652800;                // bytes per padded buffer
  _Float16* X1  = (_Float16*)ws;            // nbr padded (conv1 in + DCN sample src)
  _Float16* X2  = (_Float16*)(ws + PB);     // ref padded
  _Float16* B64 = (_Float16*)(ws + 2 * PB); // conv1 out / conv3 out
  _Float16* C64 = (_Float16*)(ws + 3 * PB); // conv2 out
  char* p = ws + 4 * PB;
  _Float16* wF1 = (_Float16*)p;  p += (size_t)73728 * 2;
  _Float16* wF2 = (_Float16*)p;  p += (size_t)36864 * 2;
  _Float16* wF3 = (_Float16*)p;  p += (size_t)36864 * 2;
  _Float16* wFo = (_Float16*)p;  p += (size_t)18432 * 2;
  _Float16* wFd = (_Float16*)p;

  // 5 dispatches total
  setup_kernel<<<dim3(3098), 256, 0, stream>>>(nbr, refp, w1, w2, w3, w_off, w_dcn,
                                               X1, X2, B64, C64, wF1, wF2, wF3, wFo, wFd);
  conv3x3_ks_kernel<4, true><<<dim3(512), 256, 0, stream>>>(X1, X2, wF1, b1, B64);
  conv3x3_ks_kernel<2, false><<<dim3(512), 256, 0, stream>>>(B64, nullptr, wF2, b2, C64);
  conv3x3_ks_kernel<2, false><<<dim3(512), 256, 0, stream>>>(C64, nullptr, wF3, b3, B64);
  off_dcn_kernel<<<dim3(1024), 256, 0, stream>>>(B64, X1, wFo, b_off, wFd, b_dcn,
                                                 offp, mskp, feat);
}

// Round 5
// 203.160 us; speedup vs baseline: 1.4580x; 1.1276x over previous
//
#include <hip/hip_runtime.h>
#include <math.h>

// Problem constants: B=4, NF=64, H=W=128, K=9
// d_in order: nbr, ref, w1, b1, w2, b2, w3, b3, w_off, b_off, w_dcn, b_dcn
// d_out: feat [4,64,128,128] | offset [4,18,128,128] | mask [4,9,128,128]

typedef _Float16 h8 __attribute__((ext_vector_type(8)));  // 8 f16 (4 VGPRs)
typedef _Float16 h4 __attribute__((ext_vector_type(4)));  // 4 f16 (2 VGPRs)
typedef _Float16 h2 __attribute__((ext_vector_type(2)));  // packed f16 pair
typedef float f4 __attribute__((ext_vector_type(4)));     // 4 fp32 acc

// ================ merged setup: weight prep + border zero + input prep ================
__global__ __launch_bounds__(256) void setup_kernel(
    const float* __restrict__ nbr, const float* __restrict__ refp,
    const float* __restrict__ w1, const float* __restrict__ w2,
    const float* __restrict__ w3, const float* __restrict__ w_off,
    const float* __restrict__ w_dcn,
    _Float16* __restrict__ X1, _Float16* __restrict__ X2,
    _Float16* __restrict__ B64, _Float16* __restrict__ C64,
    _Float16* __restrict__ wF1, _Float16* __restrict__ wF2,
    _Float16* __restrict__ wF3, _Float16* __restrict__ wFo,
    _Float16* __restrict__ wFd) {
  __shared__ float t[64 * 65];
  int bid = blockIdx.x;
  int tid = threadIdx.x;
  if (bid < 792) {
    int i = bid * 256 + tid;
    if (i < 73728) {                       // w1: NCH=4 (128 IC)
      int j = i;
      int icw = j & 31; int t1 = j >> 5; int oc = t1 & 63; int t2 = t1 >> 6;
      int ch = t2 & 3; int tap = t2 >> 2; int ic = ch * 32 + icw;
      wF1[j] = (_Float16)w1[(oc * 128 + ic) * 9 + tap];
    } else if (i < 110592) {               // w2
      int j = i - 73728;
      int icw = j & 31; int t1 = j >> 5; int oc = t1 & 63; int t2 = t1 >> 6;
      int ch = t2 & 1; int tap = t2 >> 1; int ic = ch * 32 + icw;
      wF2[j] = (_Float16)w2[(oc * 64 + ic) * 9 + tap];
    } else if (i < 147456) {               // w3
      int j = i - 110592;
      int icw = j & 31; int t1 = j >> 5; int oc = t1 & 63; int t2 = t1 >> 6;
      int ch = t2 & 1; int tap = t2 >> 1; int ic = ch * 32 + icw;
      wF3[j] = (_Float16)w3[(oc * 64 + ic) * 9 + tap];
    } else if (i < 165888) {               // w_off -> A-frag contiguous [tap*2+c][mt][lane][8]
      int jj = i - 147456;                 // 18432 = 18 * 1024
      int pc = jj >> 10;                   // tap*2+c
      int mt = (jj >> 9) & 1;
      int Lx = (jj >> 3) & 63;
      int e  = jj & 7;
      int tap = pc >> 1, c = pc & 1;
      int oc = mt * 16 + (Lx & 15);
      int ic = c * 32 + (Lx >> 4) * 8 + e;
      float v = (oc < 27) ? w_off[(oc * 64 + ic) * 9 + tap] : 0.f;
      wFo[jj] = (_Float16)v;
    } else if (i < 202752) {               // w_dcn -> A-frag contiguous [k*2+s][mt 4][lane][8]
      int jj = i - 165888;                 // 36864 = 18 * 2048
      int ks = jj >> 11;                   // k*2+s
      int mt = (jj >> 9) & 3;
      int Lx = (jj >> 3) & 63;
      int e  = jj & 7;
      int k = ks >> 1, s = ks & 1;
      int oc = mt * 16 + (Lx & 15);
      int ch = s * 32 + (Lx >> 4) * 8 + e;
      wFd[jj] = (_Float16)w_dcn[(oc * 64 + ch) * 9 + k];
    }
    return;
  }
  if (bid < 1050) {
    int i = (bid - 792) * 256 + tid;       // 66048 = 4 buf * 4 b * 516 px * 8 chunks
    int bufi = i / 16512;
    int j = i - bufi * 16512;
    int b = j / 4128;
    int r = j - b * 4128;
    int p = r >> 3; int cg = r & 7;
    int row, col;
    if (p < 130)      { row = 0;   col = p; }
    else if (p < 260) { row = 129; col = p - 130; }
    else if (p < 388) { row = 1 + (p - 260); col = 0; }
    else              { row = 1 + (p - 388); col = 129; }
    _Float16* dst = (bufi == 0) ? X1 : (bufi == 1) ? X2 : (bufi == 2) ? B64 : C64;
    uint4 z; z.x = z.y = z.z = z.w = 0u;
    *(uint4*)(dst + ((size_t)(b * 130 + row) * 130 + col) * 64 + cg * 8) = z;
    return;
  }
  // ---- input prep: fp32 NCHW -> padded NHWC f16 (64-px half-rows)
  int j = bid - 1050;                      // 2048 = 2 src * 4 b * 128 y * 2 half
  int half = j & 1;
  int y = (j >> 1) & 127;
  int b = (j >> 8) & 3;
  int src = j >> 10;
  const float* sp = src ? refp : nbr;
  _Float16* dst = src ? X2 : X1;
  for (int l = tid; l < 64 * 64; l += 256) {
    int c = l >> 6, gx = l & 63;
    t[c * 65 + gx] = sp[(((size_t)b * 64 + c) << 14) + (y << 7) + half * 64 + gx];
  }
  __syncthreads();
  unsigned* dstU = (unsigned*)dst;
  for (int l = tid; l < 64 * 32; l += 256) {
    int pxl = l >> 5, c2 = l & 31;
    union { _Float16 h[2]; unsigned u; } pk;
    pk.h[0] = (_Float16)t[(2 * c2) * 65 + pxl];
    pk.h[1] = (_Float16)t[(2 * c2 + 1) * 65 + pxl];
    dstU[((size_t)(b * 130 + y + 1) * 130 + 1 + half * 64 + pxl) * 32 + c2] = pk.u;
  }
}

// ================ LDS-staged conv: block = 64px x 64oc, 2 waves (each 32oc x 64px).
// The 3-row x 72-px x 64-ch input slab (27.6KB) is staged ONCE per block via async
// global_load_lds_dwordx4 (27 issues, 1 vmcnt(0)+barrier) -> the 9-tap K-loop is
// LDS-only for B. This removes the serialized global-load chain that kept the old
// convs at ~45us (compiler MLP ~2-4: 144 loads x ~400-900cyc exposed latency).
// Row-major [px][128B] LDS = 16-way bank conflict -> XOR-swizzle chunk^=(px&7),
// applied on the GLOBAL SOURCE address (gload_lds dest must stay linear, m173
// pattern) and identically on the ds_read address (involution).
// SPLIT (conv1, 128 IC): stage X1 slab, compute c=0,1; restage X2; compute c=2,3.
template <int NCH, bool SPLIT>
__global__ __launch_bounds__(128, 4) void conv3x3_lds_kernel(
    const _Float16* __restrict__ X1, const _Float16* __restrict__ X2,
    const _Float16* __restrict__ W, const float* __restrict__ bias,
    _Float16* __restrict__ outP) {
  __shared__ _Float16 Lb[3 * 72 * 64];    // 27648 B slab [row 3][px 72][ch 64], swizzled
  int tid = threadIdx.x;
  int wv = tid >> 6, L = tid & 63;
  int lm = L & 15, lq = L >> 4;
  int bid = blockIdx.x;                   // 1024 = 8 xcd * (2 half * 16 ystrip * 4 b)
  int xcd = bid & 7, j = bid >> 3;
  int half = j & 1;
  int y = (xcd << 4) | ((j >> 1) & 15);
  int b = j >> 5;
  int px0 = half * 64;

  // async stage: slab rows = padded rows y..y+2, padded cols px0..px0+71
  // (6-px tail overrun per row reads following mapped ws data; values unused)
  auto stage = [&](const _Float16* Xsrc) {
    const char* Xb = (const char*)Xsrc;
    size_t rb0 = ((size_t)(b * 130 + y) * 130 + px0) * 128;  // byte offset of slab row 0
    for (int i = wv; i < 27; i += 2) {
      int o = i * 1024 + L * 16;          // this lane's LDS byte position
      int row = o / 9216;                 // 9216 = 72 px * 128 B
      int orow = o - row * 9216;
      int px = orow >> 7;
      int c2 = (orow >> 4) & 7;
      size_t src = rb0 + (size_t)row * 16640 + (size_t)(px << 7) + (((c2 ^ (px & 7))) << 4);
      __builtin_amdgcn_global_load_lds(
          (const __attribute__((address_space(1))) void*)(Xb + src),
          (__attribute__((address_space(3))) void*)((char*)Lb + i * 1024), 16, 0, 0);
    }
  };

  f4 acc[2][4];
#pragma unroll
  for (int m = 0; m < 2; ++m)
#pragma unroll
    for (int n = 0; n < 4; ++n) acc[m][n] = (f4)0.f;

  // one compute pass over 2 c-chunks (ci = LDS ch-half), weights indexed by cbase+ci
  auto compute = [&](int cbase) {
#pragma unroll
    for (int ci = 0; ci < 2; ++ci) {
      int c = cbase + ci;
#pragma unroll
      for (int tg = 0; tg < 3; ++tg) {
        h8 a[6];
#pragma unroll
        for (int t = 0; t < 3; ++t) {
          int tap = tg * 3 + t;
          const _Float16* wp = W + (size_t)((tap * NCH + c) * 64 + wv * 32 + lm) * 32 + lq * 8;
          a[2 * t]     = *(const h8*)(wp);
          a[2 * t + 1] = *(const h8*)(wp + 512);
        }
#pragma unroll
        for (int t = 0; t < 3; ++t) {
          int tap = tg * 3 + t;
          const int dy = tap / 3, dx = tap % 3;   // dy,dx in 0..2 (row idx / col shift)
          h8 bf[4];
#pragma unroll
          for (int g = 0; g < 4; ++g) {
            int pxcol = g * 16 + lm + dx;         // slab col, 0..65
            int chunk = (ci * 4 + lq) ^ (pxcol & 7);
            int off = dy * 9216 + (pxcol << 7) + (chunk << 4);
            bf[g] = *(const h8*)((const char*)Lb + off);
          }
#pragma unroll
          for (int g = 0; g < 4; ++g) {
            acc[0][g] = __builtin_amdgcn_mfma_f32_16x16x32_f16(a[2 * t], bf[g], acc[0][g], 0, 0, 0);
            acc[1][g] = __builtin_amdgcn_mfma_f32_16x16x32_f16(a[2 * t + 1], bf[g], acc[1][g], 0, 0, 0);
          }
        }
      }
    }
  };

  stage(SPLIT ? X1 : X1);
  asm volatile("s_waitcnt vmcnt(0)" ::: "memory");
  __syncthreads();
  compute(0);
  if (SPLIT) {
    __syncthreads();                       // all waves done reading slab
    stage(X2);
    asm volatile("s_waitcnt vmcnt(0)" ::: "memory");
    __syncthreads();
    compute(2);
  }

  // epilogue: bias + lrelu -> padded NHWC f16
  const size_t obase = ((size_t)(b * 130 + (y + 1)) * 130 + 1 + px0) * 64;
#pragma unroll
  for (int mt = 0; mt < 2; ++mt)
#pragma unroll
    for (int nt = 0; nt < 4; ++nt) {
      int px = nt * 16 + lm;
      h4 pk;
#pragma unroll
      for (int r = 0; r < 4; ++r) {
        int oc = wv * 32 + mt * 16 + lq * 4 + r;
        float v = acc[mt][nt][r] + bias[oc];
        v = (v >= 0.f) ? v : 0.1f * v;
        pk[r] = (_Float16)v;
      }
      *(h4*)(outP + obase + (size_t)px * 64 + wv * 32 + mt * 16 + lq * 4) = pk;
    }
}

// ================ FUSED conv_off + DCN (r4 form, frozen: 68us proven).
__global__ __launch_bounds__(256, 4) void off_dcn_kernel(
    const _Float16* __restrict__ Xc, const _Float16* __restrict__ Xs,
    const _Float16* __restrict__ Wo, const float* __restrict__ bo,
    const _Float16* __restrict__ wD, const float* __restrict__ bd,
    float* __restrict__ off_out, float* __restrict__ mask_out,
    float* __restrict__ out) {
  __shared__ float Soff[4][16][28];     // per-WAVE slice: [px][0..17]=off, [18..26]=mask
  int tid = threadIdx.x;
  int wv = tid >> 6, L = tid & 63;
  int lm = L & 15, lq = L >> 4;
  int lq8 = lq * 8;
  int g = blockIdx.x;                   // 1024 = 8 xcd * (2 half * 16 ystrip * 4 b)
  int xcd = g & 7;
  int r0 = g >> 3;
  int half = r0 & 1;
  int y = (xcd << 4) | ((r0 >> 1) & 15);
  int b = r0 >> 5;
  int px0 = half * 64 + wv * 16;        // wave's 16-px tile base
  int gpx = px0 + lm;                   // this lane's pixel
  int hw = (y << 7) + gpx;
  int rb = b * 130;

  // ---- phase 1: conv_off (32 oc x 16 px) for this wave's pixels
  {
    f4 oa[2];
    oa[0] = (f4)0.f; oa[1] = (f4)0.f;
#pragma unroll
    for (int c = 0; c < 2; ++c)
#pragma unroll
      for (int tap = 0; tap < 9; ++tap) {
        const int dy = tap / 3 - 1, dx = tap % 3 - 1;
        const _Float16* xb = Xc + ((size_t)((rb + (y + 1 + dy)) * 130) + (1 + dx) + px0) * 64
                                + c * 32 + lq8;
        h8 b0 = *(const h8*)(xb + lm * 64);
        const _Float16* wp = Wo + (size_t)(tap * 2 + c) * 1024 + L * 8;
        h8 a0 = *(const h8*)(wp);
        h8 a1 = *(const h8*)(wp + 512);
        oa[0] = __builtin_amdgcn_mfma_f32_16x16x32_f16(a0, b0, oa[0], 0, 0, 0);
        oa[1] = __builtin_amdgcn_mfma_f32_16x16x32_f16(a1, b0, oa[1], 0, 0, 0);
      }
#pragma unroll
    for (int mt = 0; mt < 2; ++mt)
#pragma unroll
      for (int r = 0; r < 4; ++r) {
        int oc = mt * 16 + lq * 4 + r;
        if (oc < 18) {
          float v = 15.f * tanhf(oa[mt][r] + bo[oc]);
          off_out[((b * 18 + oc) << 14) + hw] = v;
          Soff[wv][lm][oc] = v;
        } else if (oc < 27) {
          float v = 1.f / (1.f + expf(-(oa[mt][r] + bo[oc])));
          mask_out[((b * 9 + (oc - 18)) << 14) + hw] = v;
          Soff[wv][lm][oc] = v;
        }
      }
  }
  // no __syncthreads: Soff slice is written and read by the SAME wave (lgkmcnt order).

  // ---- phase 2: DCN, 3 groups of 3 taps, 12-gather batches
  f4 acc[4];
#pragma unroll
  for (int mm = 0; mm < 4; ++mm) acc[mm] = (f4)0.f;

  const char* Xb = (const char*)Xs;
  const int cbL = lq8 * 2;              // lane channel byte offset within pixel block

#pragma unroll
  for (int gp = 0; gp < 3; ++gp) {
    // --- per-group params into registers (static idx after unroll)
    float soy[3], sox[3], som[3];
#pragma unroll
    for (int t = 0; t < 3; ++t) {
      const int k = gp * 3 + t;
      soy[t] = Soff[wv][lm][2 * k];
      sox[t] = Soff[wv][lm][2 * k + 1];
      som[t] = Soff[wv][lm][18 + k];
    }
    int ro0[3], ro1[3], co0[3], co1[3];
    h2 Wc00[3], Wc01[3], Wc10[3], Wc11[3];
#pragma unroll
    for (int t = 0; t < 3; ++t) {
      const int k = gp * 3 + t;
      const int kr = k / 3, kc = k - kr * 3;
      float py = (float)(y + kr - 1) + soy[t];
      float pxf = (float)(gpx + kc - 1) + sox[t];
      float fy = floorf(py), fx = floorf(pxf);
      float wy = py - fy, wx = pxf - fx;
      int y0 = (int)fy, x0 = (int)fx;
      int y1 = y0 + 1, x1 = x0 + 1;
      float vy0 = ((unsigned)y0 < 128u) ? 1.f : 0.f;
      float vy1 = ((unsigned)y1 < 128u) ? 1.f : 0.f;
      float vx0 = ((unsigned)x0 < 128u) ? 1.f : 0.f;
      float vx1 = ((unsigned)x1 < 128u) ? 1.f : 0.f;
      float ey = 1.f - wy, ex = 1.f - wx;
      float mk = som[t];
      _Float16 w00 = (_Float16)(ey * ex * mk * vy0 * vx0);
      _Float16 w01 = (_Float16)(ey * wx * mk * vy0 * vx1);
      _Float16 w10 = (_Float16)(wy * ex * mk * vy1 * vx0);
      _Float16 w11 = (_Float16)(wy * wx * mk * vy1 * vx1);
      Wc00[t] = (h2){w00, w00}; Wc01[t] = (h2){w01, w01};
      Wc10[t] = (h2){w10, w10}; Wc11[t] = (h2){w11, w11};
      int y0c = min(max(y0, 0), 127) + 1, y1c = min(max(y1, 0), 127) + 1;
      int x0c = min(max(x0, 0), 127) + 1, x1c = min(max(x1, 0), 127) + 1;
      ro0[t] = (rb + y0c) * 16640;      // 130 px * 128 B per row
      ro1[t] = (rb + y1c) * 16640;
      co0[t] = x0c * 128;
      co1[t] = x1c * 128;
    }
    // --- per channel-slice: batch-issue all 12 gathers, then combine+MFMA per tap
#pragma unroll
    for (int s = 0; s < 2; ++s) {
      const int cb2 = cbL + s * 64;
      h8 gv[12];
#pragma unroll
      for (int t = 0; t < 3; ++t) {
        gv[t * 4 + 0] = *(const h8*)(Xb + (ro0[t] + co0[t] + cb2));
        gv[t * 4 + 1] = *(const h8*)(Xb + (ro0[t] + co1[t] + cb2));
        gv[t * 4 + 2] = *(const h8*)(Xb + (ro1[t] + co0[t] + cb2));
        gv[t * 4 + 3] = *(const h8*)(Xb + (ro1[t] + co1[t] + cb2));
      }
#pragma unroll
      for (int t = 0; t < 3; ++t) {
        const int k = gp * 3 + t;
        h8 bv;
#pragma unroll
        for (int j2 = 0; j2 < 4; ++j2) {
          h2 a  = {gv[t * 4 + 0][2 * j2], gv[t * 4 + 0][2 * j2 + 1]};
          h2 bb = {gv[t * 4 + 1][2 * j2], gv[t * 4 + 1][2 * j2 + 1]};
          h2 cc = {gv[t * 4 + 2][2 * j2], gv[t * 4 + 2][2 * j2 + 1]};
          h2 dd = {gv[t * 4 + 3][2 * j2], gv[t * 4 + 3][2 * j2 + 1]};
          h2 r = a * Wc00[t];
          r += bb * Wc01[t];
          r += cc * Wc10[t];
          r += dd * Wc11[t];
          bv[2 * j2] = r[0];
          bv[2 * j2 + 1] = r[1];
        }
        const _Float16* wp = wD + (size_t)(k * 2 + s) * 2048 + L * 8;
        acc[0] = __builtin_amdgcn_mfma_f32_16x16x32_f16(*(const h8*)(wp), bv, acc[0], 0, 0, 0);
        acc[1] = __builtin_amdgcn_mfma_f32_16x16x32_f16(*(const h8*)(wp + 512), bv, acc[1], 0, 0, 0);
        acc[2] = __builtin_amdgcn_mfma_f32_16x16x32_f16(*(const h8*)(wp + 1024), bv, acc[2], 0, 0, 0);
        acc[3] = __builtin_amdgcn_mfma_f32_16x16x32_f16(*(const h8*)(wp + 1536), bv, acc[3], 0, 0, 0);
      }
    }
  }

  // epilogue: bias + lrelu, fp32 NCHW
#pragma unroll
  for (int mt = 0; mt < 4; ++mt)
#pragma unroll
    for (int r = 0; r < 4; ++r) {
      int oc = mt * 16 + lq * 4 + r;
      float v = acc[mt][r] + bd[oc];
      v = (v >= 0.f) ? v : 0.1f * v;
      out[(((b << 6) + oc) << 14) + (y << 7) + gpx] = v;
    }
}

extern "C" void kernel_launch(void* const* d_in, const int* in_sizes, int n_in,
                              void* d_out, int out_size, void* d_ws, size_t ws_size,
                              hipStream_t stream) {
  const float* nbr   = (const float*)d_in[0];
  const float* refp  = (const float*)d_in[1];
  const float* w1    = (const float*)d_in[2];
  const float* b1    = (const float*)d_in[3];
  const float* w2    = (const float*)d_in[4];
  const float* b2    = (const float*)d_in[5];
  const float* w3    = (const float*)d_in[6];
  const float* b3    = (const float*)d_in[7];
  const float* w_off = (const float*)d_in[8];
  const float* b_off = (const float*)d_in[9];
  const float* w_dcn = (const float*)d_in[10];
  const float* b_dcn = (const float*)d_in[11];

  float* outp = (float*)d_out;
  float* feat = outp;                       // 4*64*16384
  float* offp = outp + 4194304;             // 4*18*16384
  float* mskp = outp + 4194304 + 1179648;   // 4*9*16384

  // ws layout: four padded NHWC f16 buffers [4][130][130][64] + f16 weights (~33.4 MiB)
  char* ws = (char*)d_ws;
  const size_t PB = 8652800;                // bytes per padded buffer
  _Float16* X1  = (_Float16*)ws;            // nbr padded (conv1 in + DCN sample src)
  _Float16* X2  = (_Float16*)(ws + PB);     // ref padded
  _Float16* B64 = (_Float16*)(ws + 2 * PB); // conv1 out / conv3 out
  _Float16* C64 = (_Float16*)(ws + 3 * PB); // conv2 out
  char* p = ws + 4 * PB;
  _Float16* wF1 = (_Float16*)p;  p += (size_t)73728 * 2;
  _Float16* wF2 = (_Float16*)p;  p += (size_t)36864 * 2;
  _Float16* wF3 = (_Float16*)p;  p += (size_t)36864 * 2;
  _Float16* wFo = (_Float16*)p;  p += (size_t)18432 * 2;
  _Float16* wFd = (_Float16*)p;

  // 5 dispatches total
  setup_kernel<<<dim3(3098), 256, 0, stream>>>(nbr, refp, w1, w2, w3, w_off, w_dcn,
                                               X1, X2, B64, C64, wF1, wF2, wF3, wFo, wFd);
  conv3x3_lds_kernel<4, true><<<dim3(1024), 128, 0, stream>>>(X1, X2, wF1, b1, B64);
  conv3x3_lds_kernel<2, false><<<dim3(1024), 128, 0, stream>>>(B64, nullptr, wF2, b2, C64);
  conv3x3_lds_kernel<2, false><<<dim3(1024), 128, 0, stream>>>(C64, nullptr, wF3, b3, B64);
  off_dcn_kernel<<<dim3(1024), 256, 0, stream>>>(B64, X1, wFo, b_off, wFd, b_dcn,
                                                 offp, mskp, feat);
}

// Round 6
// 202.460 us; speedup vs baseline: 1.4630x; 1.0035x over previous
//
#include <hip/hip_runtime.h>
#include <math.h>

// Problem constants: B=4, NF=64, H=W=128, K=9
// d_in order: nbr, ref, w1, b1, w2, b2, w3, b3, w_off, b_off, w_dcn, b_dcn
// d_out: feat [4,64,128,128] | offset [4,18,128,128] | mask [4,9,128,128]

typedef _Float16 h8 __attribute__((ext_vector_type(8)));  // 8 f16 (4 VGPRs)
typedef _Float16 h4 __attribute__((ext_vector_type(4)));  // 4 f16 (2 VGPRs)
typedef _Float16 h2 __attribute__((ext_vector_type(2)));  // packed f16 pair
typedef float f4 __attribute__((ext_vector_type(4)));     // 4 fp32 acc

// ================ merged setup: weight prep + border zero + input prep ================
__global__ __launch_bounds__(256) void setup_kernel(
    const float* __restrict__ nbr, const float* __restrict__ refp,
    const float* __restrict__ w1, const float* __restrict__ w2,
    const float* __restrict__ w3, const float* __restrict__ w_off,
    const float* __restrict__ w_dcn,
    _Float16* __restrict__ X1, _Float16* __restrict__ X2,
    _Float16* __restrict__ B64, _Float16* __restrict__ C64,
    _Float16* __restrict__ wF1, _Float16* __restrict__ wF2,
    _Float16* __restrict__ wF3, _Float16* __restrict__ wFo,
    _Float16* __restrict__ wFd) {
  __shared__ float t[64 * 65];
  int bid = blockIdx.x;
  int tid = threadIdx.x;
  if (bid < 792) {
    int i = bid * 256 + tid;
    if (i < 73728) {                       // w1: NCH=4 (128 IC)
      int j = i;
      int icw = j & 31; int t1 = j >> 5; int oc = t1 & 63; int t2 = t1 >> 6;
      int ch = t2 & 3; int tap = t2 >> 2; int ic = ch * 32 + icw;
      wF1[j] = (_Float16)w1[(oc * 128 + ic) * 9 + tap];
    } else if (i < 110592) {               // w2
      int j = i - 73728;
      int icw = j & 31; int t1 = j >> 5; int oc = t1 & 63; int t2 = t1 >> 6;
      int ch = t2 & 1; int tap = t2 >> 1; int ic = ch * 32 + icw;
      wF2[j] = (_Float16)w2[(oc * 64 + ic) * 9 + tap];
    } else if (i < 147456) {               // w3
      int j = i - 110592;
      int icw = j & 31; int t1 = j >> 5; int oc = t1 & 63; int t2 = t1 >> 6;
      int ch = t2 & 1; int tap = t2 >> 1; int ic = ch * 32 + icw;
      wF3[j] = (_Float16)w3[(oc * 64 + ic) * 9 + tap];
    } else if (i < 165888) {               // w_off -> A-frag contiguous [tap*2+c][mt][lane][8]
      int jj = i - 147456;                 // 18432 = 18 * 1024
      int pc = jj >> 10;                   // tap*2+c
      int mt = (jj >> 9) & 1;
      int Lx = (jj >> 3) & 63;
      int e  = jj & 7;
      int tap = pc >> 1, c = pc & 1;
      int oc = mt * 16 + (Lx & 15);
      int ic = c * 32 + (Lx >> 4) * 8 + e;
      float v = (oc < 27) ? w_off[(oc * 64 + ic) * 9 + tap] : 0.f;
      wFo[jj] = (_Float16)v;
    } else if (i < 202752) {               // w_dcn -> A-frag contiguous [k*2+s][mt 4][lane][8]
      int jj = i - 165888;                 // 36864 = 18 * 2048
      int ks = jj >> 11;                   // k*2+s
      int mt = (jj >> 9) & 3;
      int Lx = (jj >> 3) & 63;
      int e  = jj & 7;
      int k = ks >> 1, s = ks & 1;
      int oc = mt * 16 + (Lx & 15);
      int ch = s * 32 + (Lx >> 4) * 8 + e;
      wFd[jj] = (_Float16)w_dcn[(oc * 64 + ch) * 9 + k];
    }
    return;
  }
  if (bid < 1050) {
    int i = (bid - 792) * 256 + tid;       // 66048 = 4 buf * 4 b * 516 px * 8 chunks
    int bufi = i / 16512;
    int j = i - bufi * 16512;
    int b = j / 4128;
    int r = j - b * 4128;
    int p = r >> 3; int cg = r & 7;
    int row, col;
    if (p < 130)      { row = 0;   col = p; }
    else if (p < 260) { row = 129; col = p - 130; }
    else if (p < 388) { row = 1 + (p - 260); col = 0; }
    else              { row = 1 + (p - 388); col = 129; }
    _Float16* dst = (bufi == 0) ? X1 : (bufi == 1) ? X2 : (bufi == 2) ? B64 : C64;
    uint4 z; z.x = z.y = z.z = z.w = 0u;
    *(uint4*)(dst + ((size_t)(b * 130 + row) * 130 + col) * 64 + cg * 8) = z;
    return;
  }
  // ---- input prep: fp32 NCHW -> padded NHWC f16 (64-px half-rows)
  int j = bid - 1050;                      // 2048 = 2 src * 4 b * 128 y * 2 half
  int half = j & 1;
  int y = (j >> 1) & 127;
  int b = (j >> 8) & 3;
  int src = j >> 10;
  const float* sp = src ? refp : nbr;
  _Float16* dst = src ? X2 : X1;
  for (int l = tid; l < 64 * 64; l += 256) {
    int c = l >> 6, gx = l & 63;
    t[c * 65 + gx] = sp[(((size_t)b * 64 + c) << 14) + (y << 7) + half * 64 + gx];
  }
  __syncthreads();
  unsigned* dstU = (unsigned*)dst;
  for (int l = tid; l < 64 * 32; l += 256) {
    int pxl = l >> 5, c2 = l & 31;
    union { _Float16 h[2]; unsigned u; } pk;
    pk.h[0] = (_Float16)t[(2 * c2) * 65 + pxl];
    pk.h[1] = (_Float16)t[(2 * c2 + 1) * 65 + pxl];
    dstU[((size_t)(b * 130 + y + 1) * 130 + 1 + half * 64 + pxl) * 32 + c2] = pk.u;
  }
}

// ================ LDS-staged conv (r5 form, frozen): block = 64px x 64oc, 2 waves.
template <int NCH, bool SPLIT>
__global__ __launch_bounds__(128, 4) void conv3x3_lds_kernel(
    const _Float16* __restrict__ X1, const _Float16* __restrict__ X2,
    const _Float16* __restrict__ W, const float* __restrict__ bias,
    _Float16* __restrict__ outP) {
  __shared__ _Float16 Lb[3 * 72 * 64];    // 27648 B slab [row 3][px 72][ch 64], swizzled
  int tid = threadIdx.x;
  int wv = tid >> 6, L = tid & 63;
  int lm = L & 15, lq = L >> 4;
  int bid = blockIdx.x;                   // 1024 = 8 xcd * (2 half * 16 ystrip * 4 b)
  int xcd = bid & 7, j = bid >> 3;
  int half = j & 1;
  int y = (xcd << 4) | ((j >> 1) & 15);
  int b = j >> 5;
  int px0 = half * 64;

  auto stage = [&](const _Float16* Xsrc) {
    const char* Xb = (const char*)Xsrc;
    size_t rb0 = ((size_t)(b * 130 + y) * 130 + px0) * 128;  // byte offset of slab row 0
    for (int i = wv; i < 27; i += 2) {
      int o = i * 1024 + L * 16;
      int row = o / 9216;                 // 9216 = 72 px * 128 B
      int orow = o - row * 9216;
      int px = orow >> 7;
      int c2 = (orow >> 4) & 7;
      size_t src = rb0 + (size_t)row * 16640 + (size_t)(px << 7) + (((c2 ^ (px & 7))) << 4);
      __builtin_amdgcn_global_load_lds(
          (const __attribute__((address_space(1))) void*)(Xb + src),
          (__attribute__((address_space(3))) void*)((char*)Lb + i * 1024), 16, 0, 0);
    }
  };

  f4 acc[2][4];
#pragma unroll
  for (int m = 0; m < 2; ++m)
#pragma unroll
    for (int n = 0; n < 4; ++n) acc[m][n] = (f4)0.f;

  auto compute = [&](int cbase) {
#pragma unroll
    for (int ci = 0; ci < 2; ++ci) {
      int c = cbase + ci;
#pragma unroll
      for (int tg = 0; tg < 3; ++tg) {
        h8 a[6];
#pragma unroll
        for (int t = 0; t < 3; ++t) {
          int tap = tg * 3 + t;
          const _Float16* wp = W + (size_t)((tap * NCH + c) * 64 + wv * 32 + lm) * 32 + lq * 8;
          a[2 * t]     = *(const h8*)(wp);
          a[2 * t + 1] = *(const h8*)(wp + 512);
        }
#pragma unroll
        for (int t = 0; t < 3; ++t) {
          int tap = tg * 3 + t;
          const int dy = tap / 3, dx = tap % 3;
          h8 bf[4];
#pragma unroll
          for (int g = 0; g < 4; ++g) {
            int pxcol = g * 16 + lm + dx;
            int chunk = (ci * 4 + lq) ^ (pxcol & 7);
            int off = dy * 9216 + (pxcol << 7) + (chunk << 4);
            bf[g] = *(const h8*)((const char*)Lb + off);
          }
#pragma unroll
          for (int g = 0; g < 4; ++g) {
            acc[0][g] = __builtin_amdgcn_mfma_f32_16x16x32_f16(a[2 * t], bf[g], acc[0][g], 0, 0, 0);
            acc[1][g] = __builtin_amdgcn_mfma_f32_16x16x32_f16(a[2 * t + 1], bf[g], acc[1][g], 0, 0, 0);
          }
        }
      }
    }
  };

  stage(X1);
  asm volatile("s_waitcnt vmcnt(0)" ::: "memory");
  __syncthreads();
  compute(0);
  if (SPLIT) {
    __syncthreads();
    stage(X2);
    asm volatile("s_waitcnt vmcnt(0)" ::: "memory");
    __syncthreads();
    compute(2);
  }

  const size_t obase = ((size_t)(b * 130 + (y + 1)) * 130 + 1 + px0) * 64;
#pragma unroll
  for (int mt = 0; mt < 2; ++mt)
#pragma unroll
    for (int nt = 0; nt < 4; ++nt) {
      int px = nt * 16 + lm;
      h4 pk;
#pragma unroll
      for (int r = 0; r < 4; ++r) {
        int oc = wv * 32 + mt * 16 + lq * 4 + r;
        float v = acc[mt][nt][r] + bias[oc];
        v = (v >= 0.f) ? v : 0.1f * v;
        pk[r] = (_Float16)v;
      }
      *(h4*)(outP + obase + (size_t)px * 64 + wv * 32 + mt * 16 + lq * 4) = pk;
    }
}

// ================ FUSED conv_off + DCN: r4 structure + ISA-forced load batching.
// r5 counters: 130k of 163k cycles are memory-wait at ~215cyc/load -> effective MLP
// ~1/wave despite source-level gv[12] batches (compiler clumps them; VGPR=64 chosen).
// Fix at ISA level: ONE asm block issues 12 global_load_dwordx4 back-to-back and
// ends with s_waitcnt vmcnt(0). "=&v" early-clobber outputs guarantee no dest/addr
// aliasing within the batch; the wait INSIDE the asm means no use can be hoisted
// above it (rule-#18 safe) and no async-dest hazard crosses statements. Phase 1
// gets the same treatment (9-deep per c). Everything else identical to r4/r5.
__global__ __launch_bounds__(256, 4) void off_dcn_kernel(
    const _Float16* __restrict__ Xc, const _Float16* __restrict__ Xs,
    const _Float16* __restrict__ Wo, const float* __restrict__ bo,
    const _Float16* __restrict__ wD, const float* __restrict__ bd,
    float* __restrict__ off_out, float* __restrict__ mask_out,
    float* __restrict__ out) {
  __shared__ float Soff[4][16][28];     // per-WAVE slice: [px][0..17]=off, [18..26]=mask
  int tid = threadIdx.x;
  int wv = tid >> 6, L = tid & 63;
  int lm = L & 15, lq = L >> 4;
  int lq8 = lq * 8;
  int g = blockIdx.x;                   // 1024 = 8 xcd * (2 half * 16 ystrip * 4 b)
  int xcd = g & 7;
  int r0 = g >> 3;
  int half = r0 & 1;
  int y = (xcd << 4) | ((r0 >> 1) & 15);
  int b = r0 >> 5;
  int px0 = half * 64 + wv * 16;        // wave's 16-px tile base
  int gpx = px0 + lm;                   // this lane's pixel
  int hw = (y << 7) + gpx;
  int rb = b * 130;

  // ---- phase 1: conv_off (32 oc x 16 px), 9-deep batched input loads per c
  {
    f4 oa[2];
    oa[0] = (f4)0.f; oa[1] = (f4)0.f;
#pragma unroll
    for (int c = 0; c < 2; ++c) {
      const void* pB[9];
#pragma unroll
      for (int tap = 0; tap < 9; ++tap) {
        const int dy = tap / 3 - 1, dx = tap % 3 - 1;
        pB[tap] = (const void*)(Xc + ((size_t)((rb + (y + 1 + dy)) * 130) + (1 + dx) + px0 + lm) * 64
                                   + c * 32 + lq8);
      }
      h8 bq[9];
      asm volatile(
          "global_load_dwordx4 %0, %9, off\n\t"
          "global_load_dwordx4 %1, %10, off\n\t"
          "global_load_dwordx4 %2, %11, off\n\t"
          "global_load_dwordx4 %3, %12, off\n\t"
          "global_load_dwordx4 %4, %13, off\n\t"
          "global_load_dwordx4 %5, %14, off\n\t"
          "global_load_dwordx4 %6, %15, off\n\t"
          "global_load_dwordx4 %7, %16, off\n\t"
          "global_load_dwordx4 %8, %17, off\n\t"
          "s_waitcnt vmcnt(0)"
          : "=&v"(bq[0]), "=&v"(bq[1]), "=&v"(bq[2]), "=&v"(bq[3]), "=&v"(bq[4]),
            "=&v"(bq[5]), "=&v"(bq[6]), "=&v"(bq[7]), "=&v"(bq[8])
          : "v"(pB[0]), "v"(pB[1]), "v"(pB[2]), "v"(pB[3]), "v"(pB[4]),
            "v"(pB[5]), "v"(pB[6]), "v"(pB[7]), "v"(pB[8])
          : "memory");
#pragma unroll
      for (int tap = 0; tap < 9; ++tap) {
        const _Float16* wp = Wo + (size_t)(tap * 2 + c) * 1024 + L * 8;
        h8 a0 = *(const h8*)(wp);
        h8 a1 = *(const h8*)(wp + 512);
        oa[0] = __builtin_amdgcn_mfma_f32_16x16x32_f16(a0, bq[tap], oa[0], 0, 0, 0);
        oa[1] = __builtin_amdgcn_mfma_f32_16x16x32_f16(a1, bq[tap], oa[1], 0, 0, 0);
      }
    }
#pragma unroll
    for (int mt = 0; mt < 2; ++mt)
#pragma unroll
      for (int r = 0; r < 4; ++r) {
        int oc = mt * 16 + lq * 4 + r;
        if (oc < 18) {
          float v = 15.f * tanhf(oa[mt][r] + bo[oc]);
          off_out[((b * 18 + oc) << 14) + hw] = v;
          Soff[wv][lm][oc] = v;
        } else if (oc < 27) {
          float v = 1.f / (1.f + expf(-(oa[mt][r] + bo[oc])));
          mask_out[((b * 9 + (oc - 18)) << 14) + hw] = v;
          Soff[wv][lm][oc] = v;
        }
      }
  }
  // no __syncthreads: Soff slice is written and read by the SAME wave (lgkmcnt order).

  // ---- phase 2: DCN, 3 groups of 3 taps, 12-deep ISA-batched gathers
  f4 acc[4];
#pragma unroll
  for (int mm = 0; mm < 4; ++mm) acc[mm] = (f4)0.f;

  const char* Xb = (const char*)Xs;
  const int cbL = lq8 * 2;              // lane channel byte offset within pixel block

#pragma unroll
  for (int gp = 0; gp < 3; ++gp) {
    // --- per-group params into registers (static idx after unroll)
    float soy[3], sox[3], som[3];
#pragma unroll
    for (int t = 0; t < 3; ++t) {
      const int k = gp * 3 + t;
      soy[t] = Soff[wv][lm][2 * k];
      sox[t] = Soff[wv][lm][2 * k + 1];
      som[t] = Soff[wv][lm][18 + k];
    }
    int ro0[3], ro1[3], co0[3], co1[3];
    h2 Wc00[3], Wc01[3], Wc10[3], Wc11[3];
#pragma unroll
    for (int t = 0; t < 3; ++t) {
      const int k = gp * 3 + t;
      const int kr = k / 3, kc = k - kr * 3;
      float py = (float)(y + kr - 1) + soy[t];
      float pxf = (float)(gpx + kc - 1) + sox[t];
      float fy = floorf(py), fx = floorf(pxf);
      float wy = py - fy, wx = pxf - fx;
      int y0 = (int)fy, x0 = (int)fx;
      int y1 = y0 + 1, x1 = x0 + 1;
      float vy0 = ((unsigned)y0 < 128u) ? 1.f : 0.f;
      float vy1 = ((unsigned)y1 < 128u) ? 1.f : 0.f;
      float vx0 = ((unsigned)x0 < 128u) ? 1.f : 0.f;
      float vx1 = ((unsigned)x1 < 128u) ? 1.f : 0.f;
      float ey = 1.f - wy, ex = 1.f - wx;
      float mk = som[t];
      _Float16 w00 = (_Float16)(ey * ex * mk * vy0 * vx0);
      _Float16 w01 = (_Float16)(ey * wx * mk * vy0 * vx1);
      _Float16 w10 = (_Float16)(wy * ex * mk * vy1 * vx0);
      _Float16 w11 = (_Float16)(wy * wx * mk * vy1 * vx1);
      Wc00[t] = (h2){w00, w00}; Wc01[t] = (h2){w01, w01};
      Wc10[t] = (h2){w10, w10}; Wc11[t] = (h2){w11, w11};
      int y0c = min(max(y0, 0), 127) + 1, y1c = min(max(y1, 0), 127) + 1;
      int x0c = min(max(x0, 0), 127) + 1, x1c = min(max(x1, 0), 127) + 1;
      ro0[t] = (rb + y0c) * 16640;      // 130 px * 128 B per row
      ro1[t] = (rb + y1c) * 16640;
      co0[t] = x0c * 128;
      co1[t] = x1c * 128;
    }
    // --- per channel-slice: ONE asm batch = 12 loads + vmcnt(0), then combine+MFMA
#pragma unroll
    for (int s = 0; s < 2; ++s) {
      const int cb2 = cbL + s * 64;
      const void* A[12];
#pragma unroll
      for (int t = 0; t < 3; ++t) {
        A[t * 4 + 0] = (const void*)(Xb + (ro0[t] + co0[t] + cb2));
        A[t * 4 + 1] = (const void*)(Xb + (ro0[t] + co1[t] + cb2));
        A[t * 4 + 2] = (const void*)(Xb + (ro1[t] + co0[t] + cb2));
        A[t * 4 + 3] = (const void*)(Xb + (ro1[t] + co1[t] + cb2));
      }
      h8 gv[12];
      asm volatile(
          "global_load_dwordx4 %0, %12, off\n\t"
          "global_load_dwordx4 %1, %13, off\n\t"
          "global_load_dwordx4 %2, %14, off\n\t"
          "global_load_dwordx4 %3, %15, off\n\t"
          "global_load_dwordx4 %4, %16, off\n\t"
          "global_load_dwordx4 %5, %17, off\n\t"
          "global_load_dwordx4 %6, %18, off\n\t"
          "global_load_dwordx4 %7, %19, off\n\t"
          "global_load_dwordx4 %8, %20, off\n\t"
          "global_load_dwordx4 %9, %21, off\n\t"
          "global_load_dwordx4 %10, %22, off\n\t"
          "global_load_dwordx4 %11, %23, off\n\t"
          "s_waitcnt vmcnt(0)"
          : "=&v"(gv[0]), "=&v"(gv[1]), "=&v"(gv[2]), "=&v"(gv[3]),
            "=&v"(gv[4]), "=&v"(gv[5]), "=&v"(gv[6]), "=&v"(gv[7]),
            "=&v"(gv[8]), "=&v"(gv[9]), "=&v"(gv[10]), "=&v"(gv[11])
          : "v"(A[0]), "v"(A[1]), "v"(A[2]), "v"(A[3]),
            "v"(A[4]), "v"(A[5]), "v"(A[6]), "v"(A[7]),
            "v"(A[8]), "v"(A[9]), "v"(A[10]), "v"(A[11])
          : "memory");
#pragma unroll
      for (int t = 0; t < 3; ++t) {
        const int k = gp * 3 + t;
        h8 bv;
#pragma unroll
        for (int j2 = 0; j2 < 4; ++j2) {
          h2 a  = {gv[t * 4 + 0][2 * j2], gv[t * 4 + 0][2 * j2 + 1]};
          h2 bb = {gv[t * 4 + 1][2 * j2], gv[t * 4 + 1][2 * j2 + 1]};
          h2 cc = {gv[t * 4 + 2][2 * j2], gv[t * 4 + 2][2 * j2 + 1]};
          h2 dd = {gv[t * 4 + 3][2 * j2], gv[t * 4 + 3][2 * j2 + 1]};
          h2 r = a * Wc00[t];
          r += bb * Wc01[t];
          r += cc * Wc10[t];
          r += dd * Wc11[t];
          bv[2 * j2] = r[0];
          bv[2 * j2 + 1] = r[1];
        }
        const _Float16* wp = wD + (size_t)(k * 2 + s) * 2048 + L * 8;
        acc[0] = __builtin_amdgcn_mfma_f32_16x16x32_f16(*(const h8*)(wp), bv, acc[0], 0, 0, 0);
        acc[1] = __builtin_amdgcn_mfma_f32_16x16x32_f16(*(const h8*)(wp + 512), bv, acc[1], 0, 0, 0);
        acc[2] = __builtin_amdgcn_mfma_f32_16x16x32_f16(*(const h8*)(wp + 1024), bv, acc[2], 0, 0, 0);
        acc[3] = __builtin_amdgcn_mfma_f32_16x16x32_f16(*(const h8*)(wp + 1536), bv, acc[3], 0, 0, 0);
      }
    }
  }

  // epilogue: bias + lrelu, fp32 NCHW
#pragma unroll
  for (int mt = 0; mt < 4; ++mt)
#pragma unroll
    for (int r = 0; r < 4; ++r) {
      int oc = mt * 16 + lq * 4 + r;
      float v = acc[mt][r] + bd[oc];
      v = (v >= 0.f) ? v : 0.1f * v;
      out[(((b << 6) + oc) << 14) + (y << 7) + gpx] = v;
    }
}

extern "C" void kernel_launch(void* const* d_in, const int* in_sizes, int n_in,
                              void* d_out, int out_size, void* d_ws, size_t ws_size,
                              hipStream_t stream) {
  const float* nbr   = (const float*)d_in[0];
  const float* refp  = (const float*)d_in[1];
  const float* w1    = (const float*)d_in[2];
  const float* b1    = (const float*)d_in[3];
  const float* w2    = (const float*)d_in[4];
  const float* b2    = (const float*)d_in[5];
  const float* w3    = (const float*)d_in[6];
  const float* b3    = (const float*)d_in[7];
  const float* w_off = (const float*)d_in[8];
  const float* b_off = (const float*)d_in[9];
  const float* w_dcn = (const float*)d_in[10];
  const float* b_dcn = (const float*)d_in[11];

  float* outp = (float*)d_out;
  float* feat = outp;                       // 4*64*16384
  float* offp = outp + 4194304;             // 4*18*16384
  float* mskp = outp + 4194304 + 1179648;   // 4*9*16384

  // ws layout: four padded NHWC f16 buffers [4][130][130][64] + f16 weights (~33.4 MiB)
  char* ws = (char*)d_ws;
  const size_t PB = 8652800;                // bytes per padded buffer
  _Float16* X1  = (_Float16*)ws;            // nbr padded (conv1 in + DCN sample src)
  _Float16* X2  = (_Float16*)(ws + PB);     // ref padded
  _Float16* B64 = (_Float16*)(ws + 2 * PB); // conv1 out / conv3 out
  _Float16* C64 = (_Float16*)(ws + 3 * PB); // conv2 out
  char* p = ws + 4 * PB;
  _Float16* wF1 = (_Float16*)p;  p += (size_t)73728 * 2;
  _Float16* wF2 = (_Float16*)p;  p += (size_t)36864 * 2;
  _Float16* wF3 = (_Float16*)p;  p += (size_t)36864 * 2;
  _Float16* wFo = (_Float16*)p;  p += (size_t)18432 * 2;
  _Float16* wFd = (_Float16*)p;

  // 5 dispatches total
  setup_kernel<<<dim3(3098), 256, 0, stream>>>(nbr, refp, w1, w2, w3, w_off, w_dcn,
                                               X1, X2, B64, C64, wF1, wF2, wF3, wFo, wFd);
  conv3x3_lds_kernel<4, true><<<dim3(1024), 128, 0, stream>>>(X1, X2, wF1, b1, B64);
  conv3x3_lds_kernel<2, false><<<dim3(1024), 128, 0, stream>>>(B64, nullptr, wF2, b2, C64);
  conv3x3_lds_kernel<2, false><<<dim3(1024), 128, 0, stream>>>(C64, nullptr, wF3, b3, B64);
  off_dcn_kernel<<<dim3(1024), 256, 0, stream>>>(B64, X1, wFo, b_off, wFd, b_dcn,
                                                 offp, mskp, feat);
}

// Round 7
// 197.197 us; speedup vs baseline: 1.5020x; 1.0267x over previous
//
#include <hip/hip_runtime.h>
#include <math.h>

// Problem constants: B=4, NF=64, H=W=128, K=9
// d_in order: nbr, ref, w1, b1, w2, b2, w3, b3, w_off, b_off, w_dcn, b_dcn
// d_out: feat [4,64,128,128] | offset [4,18,128,128] | mask [4,9,128,128]

typedef _Float16 h8 __attribute__((ext_vector_type(8)));  // 8 f16 (4 VGPRs)
typedef _Float16 h4 __attribute__((ext_vector_type(4)));  // 4 f16 (2 VGPRs)
typedef _Float16 h2 __attribute__((ext_vector_type(2)));  // packed f16 pair
typedef float f4 __attribute__((ext_vector_type(4)));     // 4 fp32 acc

// ================ merged setup: weight prep + border zero + input prep ================
__global__ __launch_bounds__(256) void setup_kernel(
    const float* __restrict__ nbr, const float* __restrict__ refp,
    const float* __restrict__ w1, const float* __restrict__ w2,
    const float* __restrict__ w3, const float* __restrict__ w_off,
    const float* __restrict__ w_dcn,
    _Float16* __restrict__ X1, _Float16* __restrict__ X2,
    _Float16* __restrict__ B64, _Float16* __restrict__ C64,
    _Float16* __restrict__ wF1, _Float16* __restrict__ wF2,
    _Float16* __restrict__ wF3, _Float16* __restrict__ wFo,
    _Float16* __restrict__ wFd) {
  __shared__ float t[64 * 65];
  int bid = blockIdx.x;
  int tid = threadIdx.x;
  if (bid < 792) {
    int i = bid * 256 + tid;
    // conv weights -> A-frag contiguous [tap*NCH+c][wv][mt][lane][8]:
    // one wave A-load = 1KB coalesced (was 16 scattered 64B segments).
    if (i < 73728) {                       // w1 (NCH=4, 128 IC)
      int j = i;
      int e = j & 7; int Lx = (j >> 3) & 63; int mt = (j >> 9) & 1; int wvx = (j >> 10) & 1;
      int pc = j >> 11;                    // tap*4+c
      int tap = pc >> 2, c = pc & 3;
      int oc = wvx * 32 + mt * 16 + (Lx & 15);
      int ic = c * 32 + ((Lx >> 4) << 3) + e;
      wF1[j] = (_Float16)w1[(oc * 128 + ic) * 9 + tap];
    } else if (i < 110592) {               // w2
      int j = i - 73728;
      int e = j & 7; int Lx = (j >> 3) & 63; int mt = (j >> 9) & 1; int wvx = (j >> 10) & 1;
      int pc = j >> 11;                    // tap*2+c
      int tap = pc >> 1, c = pc & 1;
      int oc = wvx * 32 + mt * 16 + (Lx & 15);
      int ic = c * 32 + ((Lx >> 4) << 3) + e;
      wF2[j] = (_Float16)w2[(oc * 64 + ic) * 9 + tap];
    } else if (i < 147456) {               // w3
      int j = i - 110592;
      int e = j & 7; int Lx = (j >> 3) & 63; int mt = (j >> 9) & 1; int wvx = (j >> 10) & 1;
      int pc = j >> 11;
      int tap = pc >> 1, c = pc & 1;
      int oc = wvx * 32 + mt * 16 + (Lx & 15);
      int ic = c * 32 + ((Lx >> 4) << 3) + e;
      wF3[j] = (_Float16)w3[(oc * 64 + ic) * 9 + tap];
    } else if (i < 165888) {               // w_off -> A-frag contiguous [tap*2+c][mt][lane][8]
      int jj = i - 147456;                 // 18432 = 18 * 1024
      int pc = jj >> 10;                   // tap*2+c
      int mt = (jj >> 9) & 1;
      int Lx = (jj >> 3) & 63;
      int e  = jj & 7;
      int tap = pc >> 1, c = pc & 1;
      int oc = mt * 16 + (Lx & 15);
      int ic = c * 32 + (Lx >> 4) * 8 + e;
      float v = (oc < 27) ? w_off[(oc * 64 + ic) * 9 + tap] : 0.f;
      wFo[jj] = (_Float16)v;
    } else if (i < 202752) {               // w_dcn -> A-frag contiguous [k*2+s][mt 4][lane][8]
      int jj = i - 165888;                 // 36864 = 18 * 2048
      int ks = jj >> 11;                   // k*2+s
      int mt = (jj >> 9) & 3;
      int Lx = (jj >> 3) & 63;
      int e  = jj & 7;
      int k = ks >> 1, s = ks & 1;
      int oc = mt * 16 + (Lx & 15);
      int ch = s * 32 + (Lx >> 4) * 8 + e;
      wFd[jj] = (_Float16)w_dcn[(oc * 64 + ch) * 9 + k];
    }
    return;
  }
  if (bid < 1050) {
    int i = (bid - 792) * 256 + tid;       // 66048 = 4 buf * 4 b * 516 px * 8 chunks
    int bufi = i / 16512;
    int j = i - bufi * 16512;
    int b = j / 4128;
    int r = j - b * 4128;
    int p = r >> 3; int cg = r & 7;
    int row, col;
    if (p < 130)      { row = 0;   col = p; }
    else if (p < 260) { row = 129; col = p - 130; }
    else if (p < 388) { row = 1 + (p - 260); col = 0; }
    else              { row = 1 + (p - 388); col = 129; }
    _Float16* dst = (bufi == 0) ? X1 : (bufi == 1) ? X2 : (bufi == 2) ? B64 : C64;
    uint4 z; z.x = z.y = z.z = z.w = 0u;
    *(uint4*)(dst + ((size_t)(b * 130 + row) * 130 + col) * 64 + cg * 8) = z;
    return;
  }
  // ---- input prep: fp32 NCHW -> padded NHWC f16 (64-px half-rows)
  int j = bid - 1050;                      // 2048 = 2 src * 4 b * 128 y * 2 half
  int half = j & 1;
  int y = (j >> 1) & 127;
  int b = (j >> 8) & 3;
  int src = j >> 10;
  const float* sp = src ? refp : nbr;
  _Float16* dst = src ? X2 : X1;
  for (int l = tid; l < 64 * 64; l += 256) {
    int c = l >> 6, gx = l & 63;
    t[c * 65 + gx] = sp[(((size_t)b * 64 + c) << 14) + (y << 7) + half * 64 + gx];
  }
  __syncthreads();
  unsigned* dstU = (unsigned*)dst;
  for (int l = tid; l < 64 * 32; l += 256) {
    int pxl = l >> 5, c2 = l & 31;
    union { _Float16 h[2]; unsigned u; } pk;
    pk.h[0] = (_Float16)t[(2 * c2) * 65 + pxl];
    pk.h[1] = (_Float16)t[(2 * c2 + 1) * 65 + pxl];
    dstU[((size_t)(b * 130 + y + 1) * 130 + 1 + half * 64 + pxl) * 32 + c2] = pk.u;
  }
}

// ================ LDS-staged conv (r5 structure) + A-frag-coalesced weight loads.
template <int NCH, bool SPLIT>
__global__ __launch_bounds__(128, 4) void conv3x3_lds_kernel(
    const _Float16* __restrict__ X1, const _Float16* __restrict__ X2,
    const _Float16* __restrict__ W, const float* __restrict__ bias,
    _Float16* __restrict__ outP) {
  __shared__ _Float16 Lb[3 * 72 * 64];    // 27648 B slab [row 3][px 72][ch 64], swizzled
  int tid = threadIdx.x;
  int wv = tid >> 6, L = tid & 63;
  int lm = L & 15, lq = L >> 4;
  int bid = blockIdx.x;                   // 1024 = 8 xcd * (2 half * 16 ystrip * 4 b)
  int xcd = bid & 7, j = bid >> 3;
  int half = j & 1;
  int y = (xcd << 4) | ((j >> 1) & 15);
  int b = j >> 5;
  int px0 = half * 64;

  auto stage = [&](const _Float16* Xsrc) {
    const char* Xb = (const char*)Xsrc;
    size_t rb0 = ((size_t)(b * 130 + y) * 130 + px0) * 128;  // byte offset of slab row 0
    for (int i = wv; i < 27; i += 2) {
      int o = i * 1024 + L * 16;
      int row = o / 9216;                 // 9216 = 72 px * 128 B
      int orow = o - row * 9216;
      int px = orow >> 7;
      int c2 = (orow >> 4) & 7;
      size_t src = rb0 + (size_t)row * 16640 + (size_t)(px << 7) + (((c2 ^ (px & 7))) << 4);
      __builtin_amdgcn_global_load_lds(
          (const __attribute__((address_space(1))) void*)(Xb + src),
          (__attribute__((address_space(3))) void*)((char*)Lb + i * 1024), 16, 0, 0);
    }
  };

  f4 acc[2][4];
#pragma unroll
  for (int m = 0; m < 2; ++m)
#pragma unroll
    for (int n = 0; n < 4; ++n) acc[m][n] = (f4)0.f;

  auto compute = [&](int cbase) {
#pragma unroll
    for (int ci = 0; ci < 2; ++ci) {
      int c = cbase + ci;
#pragma unroll
      for (int tg = 0; tg < 3; ++tg) {
        h8 a[6];
#pragma unroll
        for (int t = 0; t < 3; ++t) {
          int tap = tg * 3 + t;
          const _Float16* wp = W + (size_t)((tap * NCH + c) * 2 + wv) * 1024 + L * 8;
          a[2 * t]     = *(const h8*)(wp);
          a[2 * t + 1] = *(const h8*)(wp + 512);
        }
#pragma unroll
        for (int t = 0; t < 3; ++t) {
          int tap = tg * 3 + t;
          const int dy = tap / 3, dx = tap % 3;
          h8 bf[4];
#pragma unroll
          for (int g = 0; g < 4; ++g) {
            int pxcol = g * 16 + lm + dx;
            int chunk = (ci * 4 + lq) ^ (pxcol & 7);
            int off = dy * 9216 + (pxcol << 7) + (chunk << 4);
            bf[g] = *(const h8*)((const char*)Lb + off);
          }
#pragma unroll
          for (int g = 0; g < 4; ++g) {
            acc[0][g] = __builtin_amdgcn_mfma_f32_16x16x32_f16(a[2 * t], bf[g], acc[0][g], 0, 0, 0);
            acc[1][g] = __builtin_amdgcn_mfma_f32_16x16x32_f16(a[2 * t + 1], bf[g], acc[1][g], 0, 0, 0);
          }
        }
      }
    }
  };

  stage(X1);
  asm volatile("s_waitcnt vmcnt(0)" ::: "memory");
  __syncthreads();
  compute(0);
  if (SPLIT) {
    __syncthreads();
    stage(X2);
    asm volatile("s_waitcnt vmcnt(0)" ::: "memory");
    __syncthreads();
    compute(2);
  }

  const size_t obase = ((size_t)(b * 130 + (y + 1)) * 130 + 1 + px0) * 64;
#pragma unroll
  for (int mt = 0; mt < 2; ++mt)
#pragma unroll
    for (int nt = 0; nt < 4; ++nt) {
      int px = nt * 16 + lm;
      h4 pk;
#pragma unroll
      for (int r = 0; r < 4; ++r) {
        int oc = wv * 32 + mt * 16 + lq * 4 + r;
        float v = acc[mt][nt][r] + bias[oc];
        v = (v >= 0.f) ? v : 0.1f * v;
        pk[r] = (_Float16)v;
      }
      *(h4*)(outP + obase + (size_t)px * 64 + wv * 32 + mt * 16 + lq * 4) = pk;
    }
}

// ================ FUSED conv_off + DCN: line-half PAIRED gather batches.
// r6 falsified the latency/MLP theory (-3.5% from forced 12-deep batches). New model:
// L1-miss THROUGHPUT bound — each gather = 16 scattered 64B segments, all L1 misses
// (gather reach +-14px -> 550KB/tile thrashes 32KB L1), and the s=0/s=1 batches read
// the SAME 128B lines 24 loads apart -> every line missed TWICE. Fix: per-tap batch
// of 8 loads = 4 corner addrs x {offset:0, offset:64} adjacent -> second half MSHR-
// merges into the in-flight line fill. Phase-2 misses halve (1152 -> 576/wave).
__global__ __launch_bounds__(256, 4) void off_dcn_kernel(
    const _Float16* __restrict__ Xc, const _Float16* __restrict__ Xs,
    const _Float16* __restrict__ Wo, const float* __restrict__ bo,
    const _Float16* __restrict__ wD, const float* __restrict__ bd,
    float* __restrict__ off_out, float* __restrict__ mask_out,
    float* __restrict__ out) {
  __shared__ float Soff[4][16][28];     // per-WAVE slice: [px][0..17]=off, [18..26]=mask
  int tid = threadIdx.x;
  int wv = tid >> 6, L = tid & 63;
  int lm = L & 15, lq = L >> 4;
  int lq8 = lq * 8;
  int g = blockIdx.x;                   // 1024 = 8 xcd * (2 half * 16 ystrip * 4 b)
  int xcd = g & 7;
  int r0 = g >> 3;
  int half = r0 & 1;
  int y = (xcd << 4) | ((r0 >> 1) & 15);
  int b = r0 >> 5;
  int px0 = half * 64 + wv * 16;        // wave's 16-px tile base
  int gpx = px0 + lm;                   // this lane's pixel
  int hw = (y << 7) + gpx;
  int rb = b * 130;

  // ---- phase 1: conv_off (32 oc x 16 px), 9-deep batched input loads per c (r6 form)
  {
    f4 oa[2];
    oa[0] = (f4)0.f; oa[1] = (f4)0.f;
#pragma unroll
    for (int c = 0; c < 2; ++c) {
      const void* pB[9];
#pragma unroll
      for (int tap = 0; tap < 9; ++tap) {
        const int dy = tap / 3 - 1, dx = tap % 3 - 1;
        pB[tap] = (const void*)(Xc + ((size_t)((rb + (y + 1 + dy)) * 130) + (1 + dx) + px0 + lm) * 64
                                   + c * 32 + lq8);
      }
      h8 bq[9];
      asm volatile(
          "global_load_dwordx4 %0, %9, off\n\t"
          "global_load_dwordx4 %1, %10, off\n\t"
          "global_load_dwordx4 %2, %11, off\n\t"
          "global_load_dwordx4 %3, %12, off\n\t"
          "global_load_dwordx4 %4, %13, off\n\t"
          "global_load_dwordx4 %5, %14, off\n\t"
          "global_load_dwordx4 %6, %15, off\n\t"
          "global_load_dwordx4 %7, %16, off\n\t"
          "global_load_dwordx4 %8, %17, off\n\t"
          "s_waitcnt vmcnt(0)"
          : "=&v"(bq[0]), "=&v"(bq[1]), "=&v"(bq[2]), "=&v"(bq[3]), "=&v"(bq[4]),
            "=&v"(bq[5]), "=&v"(bq[6]), "=&v"(bq[7]), "=&v"(bq[8])
          : "v"(pB[0]), "v"(pB[1]), "v"(pB[2]), "v"(pB[3]), "v"(pB[4]),
            "v"(pB[5]), "v"(pB[6]), "v"(pB[7]), "v"(pB[8])
          : "memory");
#pragma unroll
      for (int tap = 0; tap < 9; ++tap) {
        const _Float16* wp = Wo + (size_t)(tap * 2 + c) * 1024 + L * 8;
        h8 a0 = *(const h8*)(wp);
        h8 a1 = *(const h8*)(wp + 512);
        oa[0] = __builtin_amdgcn_mfma_f32_16x16x32_f16(a0, bq[tap], oa[0], 0, 0, 0);
        oa[1] = __builtin_amdgcn_mfma_f32_16x16x32_f16(a1, bq[tap], oa[1], 0, 0, 0);
      }
    }
#pragma unroll
    for (int mt = 0; mt < 2; ++mt)
#pragma unroll
      for (int r = 0; r < 4; ++r) {
        int oc = mt * 16 + lq * 4 + r;
        if (oc < 18) {
          float v = 15.f * tanhf(oa[mt][r] + bo[oc]);
          off_out[((b * 18 + oc) << 14) + hw] = v;
          Soff[wv][lm][oc] = v;
        } else if (oc < 27) {
          float v = 1.f / (1.f + expf(-(oa[mt][r] + bo[oc])));
          mask_out[((b * 9 + (oc - 18)) << 14) + hw] = v;
          Soff[wv][lm][oc] = v;
        }
      }
  }
  // no __syncthreads: Soff slice is written and read by the SAME wave (lgkmcnt order).

  // ---- phase 2: DCN, 9 taps; per tap ONE asm batch: 4 corner addrs x {0,64} pairs
  f4 acc[4];
#pragma unroll
  for (int mm = 0; mm < 4; ++mm) acc[mm] = (f4)0.f;

  const char* Xb = (const char*)Xs;
  const int cbL = lq8 * 2;              // lane channel byte offset within pixel block

#pragma unroll
  for (int k = 0; k < 9; ++k) {
    const int kr = k / 3, kc = k - kr * 3;
    float oy = Soff[wv][lm][2 * k];
    float ox = Soff[wv][lm][2 * k + 1];
    float mk = Soff[wv][lm][18 + k];
    float py = (float)(y + kr - 1) + oy;
    float pxf = (float)(gpx + kc - 1) + ox;
    float fy = floorf(py), fx = floorf(pxf);
    float wy = py - fy, wx = pxf - fx;
    int y0 = (int)fy, x0 = (int)fx;
    int y1 = y0 + 1, x1 = x0 + 1;
    float vy0 = ((unsigned)y0 < 128u) ? 1.f : 0.f;
    float vy1 = ((unsigned)y1 < 128u) ? 1.f : 0.f;
    float vx0 = ((unsigned)x0 < 128u) ? 1.f : 0.f;
    float vx1 = ((unsigned)x1 < 128u) ? 1.f : 0.f;
    float ey = 1.f - wy, ex = 1.f - wx;
    _Float16 w00 = (_Float16)(ey * ex * mk * vy0 * vx0);
    _Float16 w01 = (_Float16)(ey * wx * mk * vy0 * vx1);
    _Float16 w10 = (_Float16)(wy * ex * mk * vy1 * vx0);
    _Float16 w11 = (_Float16)(wy * wx * mk * vy1 * vx1);
    h2 W00 = {w00, w00}, W01 = {w01, w01}, W10 = {w10, w10}, W11 = {w11, w11};
    int y0c = min(max(y0, 0), 127) + 1, y1c = min(max(y1, 0), 127) + 1;
    int x0c = min(max(x0, 0), 127) + 1, x1c = min(max(x1, 0), 127) + 1;
    const void* a00 = (const void*)(Xb + (rb + y0c) * 16640 + x0c * 128 + cbL);
    const void* a01 = (const void*)(Xb + (rb + y0c) * 16640 + x1c * 128 + cbL);
    const void* a10 = (const void*)(Xb + (rb + y1c) * 16640 + x0c * 128 + cbL);
    const void* a11 = (const void*)(Xb + (rb + y1c) * 16640 + x1c * 128 + cbL);
    h8 gv[8];                           // [corner 4][s 2]: gv[2c+s]
    asm volatile(
        "global_load_dwordx4 %0, %8, off\n\t"
        "global_load_dwordx4 %1, %8, off offset:64\n\t"
        "global_load_dwordx4 %2, %9, off\n\t"
        "global_load_dwordx4 %3, %9, off offset:64\n\t"
        "global_load_dwordx4 %4, %10, off\n\t"
        "global_load_dwordx4 %5, %10, off offset:64\n\t"
        "global_load_dwordx4 %6, %11, off\n\t"
        "global_load_dwordx4 %7, %11, off offset:64\n\t"
        "s_waitcnt vmcnt(0)"
        : "=&v"(gv[0]), "=&v"(gv[1]), "=&v"(gv[2]), "=&v"(gv[3]),
          "=&v"(gv[4]), "=&v"(gv[5]), "=&v"(gv[6]), "=&v"(gv[7])
        : "v"(a00), "v"(a01), "v"(a10), "v"(a11)
        : "memory");
#pragma unroll
    for (int s = 0; s < 2; ++s) {
      h8 bv;
#pragma unroll
      for (int j2 = 0; j2 < 4; ++j2) {
        h2 a  = {gv[0 + s][2 * j2], gv[0 + s][2 * j2 + 1]};
        h2 bb = {gv[2 + s][2 * j2], gv[2 + s][2 * j2 + 1]};
        h2 cc = {gv[4 + s][2 * j2], gv[4 + s][2 * j2 + 1]};
        h2 dd = {gv[6 + s][2 * j2], gv[6 + s][2 * j2 + 1]};
        h2 r = a * W00;
        r += bb * W01;
        r += cc * W10;
        r += dd * W11;
        bv[2 * j2] = r[0];
        bv[2 * j2 + 1] = r[1];
      }
      const _Float16* wp = wD + (size_t)(k * 2 + s) * 2048 + L * 8;
      acc[0] = __builtin_amdgcn_mfma_f32_16x16x32_f16(*(const h8*)(wp), bv, acc[0], 0, 0, 0);
      acc[1] = __builtin_amdgcn_mfma_f32_16x16x32_f16(*(const h8*)(wp + 512), bv, acc[1], 0, 0, 0);
      acc[2] = __builtin_amdgcn_mfma_f32_16x16x32_f16(*(const h8*)(wp + 1024), bv, acc[2], 0, 0, 0);
      acc[3] = __builtin_amdgcn_mfma_f32_16x16x32_f16(*(const h8*)(wp + 1536), bv, acc[3], 0, 0, 0);
    }
  }

  // epilogue: bias + lrelu, fp32 NCHW
#pragma unroll
  for (int mt = 0; mt < 4; ++mt)
#pragma unroll
    for (int r = 0; r < 4; ++r) {
      int oc = mt * 16 + lq * 4 + r;
      float v = acc[mt][r] + bd[oc];
      v = (v >= 0.f) ? v : 0.1f * v;
      out[(((b << 6) + oc) << 14) + (y << 7) + gpx] = v;
    }
}

extern "C" void kernel_launch(void* const* d_in, const int* in_sizes, int n_in,
                              void* d_out, int out_size, void* d_ws, size_t ws_size,
                              hipStream_t stream) {
  const float* nbr   = (const float*)d_in[0];
  const float* refp  = (const float*)d_in[1];
  const float* w1    = (const float*)d_in[2];
  const float* b1    = (const float*)d_in[3];
  const float* w2    = (const float*)d_in[4];
  const float* b2    = (const float*)d_in[5];
  const float* w3    = (const float*)d_in[6];
  const float* b3    = (const float*)d_in[7];
  const float* w_off = (const float*)d_in[8];
  const float* b_off = (const float*)d_in[9];
  const float* w_dcn = (const float*)d_in[10];
  const float* b_dcn = (const float*)d_in[11];

  float* outp = (float*)d_out;
  float* feat = outp;                       // 4*64*16384
  float* offp = outp + 4194304;             // 4*18*16384
  float* mskp = outp + 4194304 + 1179648;   // 4*9*16384

  // ws layout: four padded NHWC f16 buffers [4][130][130][64] + f16 weights (~33.4 MiB)
  char* ws = (char*)d_ws;
  const size_t PB = 8652800;                // bytes per padded buffer
  _Float16* X1  = (_Float16*)ws;            // nbr padded (conv1 in + DCN sample src)
  _Float16* X2  = (_Float16*)(ws + PB);     // ref padded
  _Float16* B64 = (_Float16*)(ws + 2 * PB); // conv1 out / conv3 out
  _Float16* C64 = (_Float16*)(ws + 3 * PB); // conv2 out
  char* p = ws + 4 * PB;
  _Float16* wF1 = (_Float16*)p;  p += (size_t)73728 * 2;
  _Float16* wF2 = (_Float16*)p;  p += (size_t)36864 * 2;
  _Float16* wF3 = (_Float16*)p;  p += (size_t)36864 * 2;
  _Float16* wFo = (_Float16*)p;  p += (size_t)18432 * 2;
  _Float16* wFd = (_Float16*)p;

  // 5 dispatches total
  setup_kernel<<<dim3(3098), 256, 0, stream>>>(nbr, refp, w1, w2, w3, w_off, w_dcn,
                                               X1, X2, B64, C64, wF1, wF2, wF3, wFo, wFd);
  conv3x3_lds_kernel<4, true><<<dim3(1024), 128, 0, stream>>>(X1, X2, wF1, b1, B64);
  conv3x3_lds_kernel<2, false><<<dim3(1024), 128, 0, stream>>>(B64, nullptr, wF2, b2, C64);
  conv3x3_lds_kernel<2, false><<<dim3(1024), 128, 0, stream>>>(C64, nullptr, wF3, b3, B64);
  off_dcn_kernel<<<dim3(1024), 256, 0, stream>>>(B64, X1, wFo, b_off, wFd, b_dcn,
                                                 offp, mskp, feat);
}

// Round 8
// 194.005 us; speedup vs baseline: 1.5268x; 1.0165x over previous
//
#include <hip/hip_runtime.h>
#include <math.h>

// Problem constants: B=4, NF=64, H=W=128, K=9
// d_in order: nbr, ref, w1, b1, w2, b2, w3, b3, w_off, b_off, w_dcn, b_dcn
// d_out: feat [4,64,128,128] | offset [4,18,128,128] | mask [4,9,128,128]

typedef _Float16 h8 __attribute__((ext_vector_type(8)));  // 8 f16 (4 VGPRs)
typedef _Float16 h4 __attribute__((ext_vector_type(4)));  // 4 f16 (2 VGPRs)
typedef _Float16 h2 __attribute__((ext_vector_type(2)));  // packed f16 pair
typedef float f4 __attribute__((ext_vector_type(4)));     // 4 fp32 acc

// ================ merged setup: weight prep + border zero + input prep ================
__global__ __launch_bounds__(256) void setup_kernel(
    const float* __restrict__ nbr, const float* __restrict__ refp,
    const float* __restrict__ w1, const float* __restrict__ w2,
    const float* __restrict__ w3, const float* __restrict__ w_off,
    const float* __restrict__ w_dcn,
    _Float16* __restrict__ X1, _Float16* __restrict__ X2,
    _Float16* __restrict__ B64, _Float16* __restrict__ C64,
    _Float16* __restrict__ wF1, _Float16* __restrict__ wF2,
    _Float16* __restrict__ wF3, _Float16* __restrict__ wFo,
    _Float16* __restrict__ wFd) {
  __shared__ float t[64 * 65];
  int bid = blockIdx.x;
  int tid = threadIdx.x;
  if (bid < 792) {
    int i = bid * 256 + tid;
    // conv weights -> A-frag contiguous [tap*NCH+c][ocH][mt][lane][8]:
    // one wave A-load = 1KB coalesced.
    if (i < 73728) {                       // w1 (NCH=4, 128 IC)
      int j = i;
      int e = j & 7; int Lx = (j >> 3) & 63; int mt = (j >> 9) & 1; int wvx = (j >> 10) & 1;
      int pc = j >> 11;                    // tap*4+c
      int tap = pc >> 2, c = pc & 3;
      int oc = wvx * 32 + mt * 16 + (Lx & 15);
      int ic = c * 32 + ((Lx >> 4) << 3) + e;
      wF1[j] = (_Float16)w1[(oc * 128 + ic) * 9 + tap];
    } else if (i < 110592) {               // w2
      int j = i - 73728;
      int e = j & 7; int Lx = (j >> 3) & 63; int mt = (j >> 9) & 1; int wvx = (j >> 10) & 1;
      int pc = j >> 11;                    // tap*2+c
      int tap = pc >> 1, c = pc & 1;
      int oc = wvx * 32 + mt * 16 + (Lx & 15);
      int ic = c * 32 + ((Lx >> 4) << 3) + e;
      wF2[j] = (_Float16)w2[(oc * 64 + ic) * 9 + tap];
    } else if (i < 147456) {               // w3
      int j = i - 110592;
      int e = j & 7; int Lx = (j >> 3) & 63; int mt = (j >> 9) & 1; int wvx = (j >> 10) & 1;
      int pc = j >> 11;
      int tap = pc >> 1, c = pc & 1;
      int oc = wvx * 32 + mt * 16 + (Lx & 15);
      int ic = c * 32 + ((Lx >> 4) << 3) + e;
      wF3[j] = (_Float16)w3[(oc * 64 + ic) * 9 + tap];
    } else if (i < 165888) {               // w_off -> A-frag contiguous [tap*2+c][mt][lane][8]
      int jj = i - 147456;                 // 18432 = 18 * 1024
      int pc = jj >> 10;                   // tap*2+c
      int mt = (jj >> 9) & 1;
      int Lx = (jj >> 3) & 63;
      int e  = jj & 7;
      int tap = pc >> 1, c = pc & 1;
      int oc = mt * 16 + (Lx & 15);
      int ic = c * 32 + (Lx >> 4) * 8 + e;
      float v = (oc < 27) ? w_off[(oc * 64 + ic) * 9 + tap] : 0.f;
      wFo[jj] = (_Float16)v;
    } else if (i < 202752) {               // w_dcn -> A-frag contiguous [k*2+s][mt 4][lane][8]
      int jj = i - 165888;                 // 36864 = 18 * 2048
      int ks = jj >> 11;                   // k*2+s
      int mt = (jj >> 9) & 3;
      int Lx = (jj >> 3) & 63;
      int e  = jj & 7;
      int k = ks >> 1, s = ks & 1;
      int oc = mt * 16 + (Lx & 15);
      int ch = s * 32 + (Lx >> 4) * 8 + e;
      wFd[jj] = (_Float16)w_dcn[(oc * 64 + ch) * 9 + k];
    }
    return;
  }
  if (bid < 1050) {
    int i = (bid - 792) * 256 + tid;       // 66048 = 4 buf * 4 b * 516 px * 8 chunks
    int bufi = i / 16512;
    int j = i - bufi * 16512;
    int b = j / 4128;
    int r = j - b * 4128;
    int p = r >> 3; int cg = r & 7;
    int row, col;
    if (p < 130)      { row = 0;   col = p; }
    else if (p < 260) { row = 129; col = p - 130; }
    else if (p < 388) { row = 1 + (p - 260); col = 0; }
    else              { row = 1 + (p - 388); col = 129; }
    _Float16* dst = (bufi == 0) ? X1 : (bufi == 1) ? X2 : (bufi == 2) ? B64 : C64;
    uint4 z; z.x = z.y = z.z = z.w = 0u;
    *(uint4*)(dst + ((size_t)(b * 130 + row) * 130 + col) * 64 + cg * 8) = z;
    return;
  }
  // ---- input prep: fp32 NCHW -> padded NHWC f16 (64-px half-rows)
  int j = bid - 1050;                      // 2048 = 2 src * 4 b * 128 y * 2 half
  int half = j & 1;
  int y = (j >> 1) & 127;
  int b = (j >> 8) & 3;
  int src = j >> 10;
  const float* sp = src ? refp : nbr;
  _Float16* dst = src ? X2 : X1;
  for (int l = tid; l < 64 * 64; l += 256) {
    int c = l >> 6, gx = l & 63;
    t[c * 65 + gx] = sp[(((size_t)b * 64 + c) << 14) + (y << 7) + half * 64 + gx];
  }
  __syncthreads();
  unsigned* dstU = (unsigned*)dst;
  for (int l = tid; l < 64 * 32; l += 256) {
    int pxl = l >> 5, c2 = l & 31;
    union { _Float16 h[2]; unsigned u; } pk;
    pk.h[0] = (_Float16)t[(2 * c2) * 65 + pxl];
    pk.h[1] = (_Float16)t[(2 * c2 + 1) * 65 + pxl];
    dstU[((size_t)(b * 130 + y + 1) * 130 + 1 + half * 64 + pxl) * 32 + c2] = pk.u;
  }
}

// ================ LDS-staged conv, 4-wave quadrant split.
// Same 64px x 64oc block + single 27.6KB slab as r5-r7, but 256 thr / 4 waves:
// wave (ocH, pxH) owns a 32oc x 32px quadrant. Per-CU MFMA/ds/stage totals
// unchanged (A-loads duplicated x2 across px-half waves: coalesced L2 hits);
// resident waves/SIMD 2.5 -> 5, halving latency exposure of the per-wave
// serial wait-points (stage drain, A-load waits). Pure-TLP experiment.
template <int NCH, bool SPLIT>
__global__ __launch_bounds__(256, 4) void conv3x3_lds_kernel(
    const _Float16* __restrict__ X1, const _Float16* __restrict__ X2,
    const _Float16* __restrict__ W, const float* __restrict__ bias,
    _Float16* __restrict__ outP) {
  __shared__ _Float16 Lb[3 * 72 * 64];    // 27648 B slab [row 3][px 72][ch 64], swizzled
  int tid = threadIdx.x;
  int wv = tid >> 6, L = tid & 63;
  int lm = L & 15, lq = L >> 4;
  int ocH = wv >> 1, pxH = wv & 1;        // wave quadrant
  int bid = blockIdx.x;                   // 1024 = 8 xcd * (2 half * 16 ystrip * 4 b)
  int xcd = bid & 7, j = bid >> 3;
  int half = j & 1;
  int y = (xcd << 4) | ((j >> 1) & 15);
  int b = j >> 5;
  int px0 = half * 64;
  int pxq = pxH * 32;                     // wave's px offset within the slab

  auto stage = [&](const _Float16* Xsrc) {
    const char* Xb = (const char*)Xsrc;
    size_t rb0 = ((size_t)(b * 130 + y) * 130 + px0) * 128;  // byte offset of slab row 0
    for (int i = wv; i < 27; i += 4) {
      int o = i * 1024 + L * 16;
      int row = o / 9216;                 // 9216 = 72 px * 128 B
      int orow = o - row * 9216;
      int px = orow >> 7;
      int c2 = (orow >> 4) & 7;
      size_t src = rb0 + (size_t)row * 16640 + (size_t)(px << 7) + (((c2 ^ (px & 7))) << 4);
      __builtin_amdgcn_global_load_lds(
          (const __attribute__((address_space(1))) void*)(Xb + src),
          (__attribute__((address_space(3))) void*)((char*)Lb + i * 1024), 16, 0, 0);
    }
  };

  f4 acc[2][2];
#pragma unroll
  for (int m = 0; m < 2; ++m)
#pragma unroll
    for (int n = 0; n < 2; ++n) acc[m][n] = (f4)0.f;

  auto compute = [&](int cbase) {
#pragma unroll
    for (int ci = 0; ci < 2; ++ci) {
      int c = cbase + ci;
#pragma unroll
      for (int tg = 0; tg < 3; ++tg) {
        h8 a[6];
#pragma unroll
        for (int t = 0; t < 3; ++t) {
          int tap = tg * 3 + t;
          const _Float16* wp = W + (size_t)((tap * NCH + c) * 2 + ocH) * 1024 + L * 8;
          a[2 * t]     = *(const h8*)(wp);
          a[2 * t + 1] = *(const h8*)(wp + 512);
        }
#pragma unroll
        for (int t = 0; t < 3; ++t) {
          int tap = tg * 3 + t;
          const int dy = tap / 3, dx = tap % 3;
          h8 bf[2];
#pragma unroll
          for (int g = 0; g < 2; ++g) {
            int pxcol = pxq + g * 16 + lm + dx;
            int chunk = (ci * 4 + lq) ^ (pxcol & 7);
            int off = dy * 9216 + (pxcol << 7) + (chunk << 4);
            bf[g] = *(const h8*)((const char*)Lb + off);
          }
#pragma unroll
          for (int g = 0; g < 2; ++g) {
            acc[0][g] = __builtin_amdgcn_mfma_f32_16x16x32_f16(a[2 * t], bf[g], acc[0][g], 0, 0, 0);
            acc[1][g] = __builtin_amdgcn_mfma_f32_16x16x32_f16(a[2 * t + 1], bf[g], acc[1][g], 0, 0, 0);
          }
        }
      }
    }
  };

  stage(X1);
  asm volatile("s_waitcnt vmcnt(0)" ::: "memory");
  __syncthreads();
  compute(0);
  if (SPLIT) {
    __syncthreads();
    stage(X2);
    asm volatile("s_waitcnt vmcnt(0)" ::: "memory");
    __syncthreads();
    compute(2);
  }

  const size_t obase = ((size_t)(b * 130 + (y + 1)) * 130 + 1 + px0) * 64;
#pragma unroll
  for (int mt = 0; mt < 2; ++mt)
#pragma unroll
    for (int nt = 0; nt < 2; ++nt) {
      int px = pxq + nt * 16 + lm;
      h4 pk;
#pragma unroll
      for (int r = 0; r < 4; ++r) {
        int oc = ocH * 32 + mt * 16 + lq * 4 + r;
        float v = acc[mt][nt][r] + bias[oc];
        v = (v >= 0.f) ? v : 0.1f * v;
        pk[r] = (_Float16)v;
      }
      *(h4*)(outP + obase + (size_t)px * 64 + ocH * 32 + mt * 16 + lq * 4) = pk;
    }
}

// ================ FUSED conv_off + DCN (r7 form, FROZEN at the gather wall:
// 4.7M 64B segments x ~8.2 cyc/seg/CU ≈ 60us floor for any L1-gather formulation).
__global__ __launch_bounds__(256, 4) void off_dcn_kernel(
    const _Float16* __restrict__ Xc, const _Float16* __restrict__ Xs,
    const _Float16* __restrict__ Wo, const float* __restrict__ bo,
    const _Float16* __restrict__ wD, const float* __restrict__ bd,
    float* __restrict__ off_out, float* __restrict__ mask_out,
    float* __restrict__ out) {
  __shared__ float Soff[4][16][28];     // per-WAVE slice: [px][0..17]=off, [18..26]=mask
  int tid = threadIdx.x;
  int wv = tid >> 6, L = tid & 63;
  int lm = L & 15, lq = L >> 4;
  int lq8 = lq * 8;
  int g = blockIdx.x;                   // 1024 = 8 xcd * (2 half * 16 ystrip * 4 b)
  int xcd = g & 7;
  int r0 = g >> 3;
  int half = r0 & 1;
  int y = (xcd << 4) | ((r0 >> 1) & 15);
  int b = r0 >> 5;
  int px0 = half * 64 + wv * 16;        // wave's 16-px tile base
  int gpx = px0 + lm;                   // this lane's pixel
  int hw = (y << 7) + gpx;
  int rb = b * 130;

  // ---- phase 1: conv_off (32 oc x 16 px), 9-deep batched input loads per c
  {
    f4 oa[2];
    oa[0] = (f4)0.f; oa[1] = (f4)0.f;
#pragma unroll
    for (int c = 0; c < 2; ++c) {
      const void* pB[9];
#pragma unroll
      for (int tap = 0; tap < 9; ++tap) {
        const int dy = tap / 3 - 1, dx = tap % 3 - 1;
        pB[tap] = (const void*)(Xc + ((size_t)((rb + (y + 1 + dy)) * 130) + (1 + dx) + px0 + lm) * 64
                                   + c * 32 + lq8);
      }
      h8 bq[9];
      asm volatile(
          "global_load_dwordx4 %0, %9, off\n\t"
          "global_load_dwordx4 %1, %10, off\n\t"
          "global_load_dwordx4 %2, %11, off\n\t"
          "global_load_dwordx4 %3, %12, off\n\t"
          "global_load_dwordx4 %4, %13, off\n\t"
          "global_load_dwordx4 %5, %14, off\n\t"
          "global_load_dwordx4 %6, %15, off\n\t"
          "global_load_dwordx4 %7, %16, off\n\t"
          "global_load_dwordx4 %8, %17, off\n\t"
          "s_waitcnt vmcnt(0)"
          : "=&v"(bq[0]), "=&v"(bq[1]), "=&v"(bq[2]), "=&v"(bq[3]), "=&v"(bq[4]),
            "=&v"(bq[5]), "=&v"(bq[6]), "=&v"(bq[7]), "=&v"(bq[8])
          : "v"(pB[0]), "v"(pB[1]), "v"(pB[2]), "v"(pB[3]), "v"(pB[4]),
            "v"(pB[5]), "v"(pB[6]), "v"(pB[7]), "v"(pB[8])
          : "memory");
#pragma unroll
      for (int tap = 0; tap < 9; ++tap) {
        const _Float16* wp = Wo + (size_t)(tap * 2 + c) * 1024 + L * 8;
        h8 a0 = *(const h8*)(wp);
        h8 a1 = *(const h8*)(wp + 512);
        oa[0] = __builtin_amdgcn_mfma_f32_16x16x32_f16(a0, bq[tap], oa[0], 0, 0, 0);
        oa[1] = __builtin_amdgcn_mfma_f32_16x16x32_f16(a1, bq[tap], oa[1], 0, 0, 0);
      }
    }
#pragma unroll
    for (int mt = 0; mt < 2; ++mt)
#pragma unroll
      for (int r = 0; r < 4; ++r) {
        int oc = mt * 16 + lq * 4 + r;
        if (oc < 18) {
          float v = 15.f * tanhf(oa[mt][r] + bo[oc]);
          off_out[((b * 18 + oc) << 14) + hw] = v;
          Soff[wv][lm][oc] = v;
        } else if (oc < 27) {
          float v = 1.f / (1.f + expf(-(oa[mt][r] + bo[oc])));
          mask_out[((b * 9 + (oc - 18)) << 14) + hw] = v;
          Soff[wv][lm][oc] = v;
        }
      }
  }
  // no __syncthreads: Soff slice is written and read by the SAME wave (lgkmcnt order).

  // ---- phase 2: DCN, 9 taps; per tap ONE asm batch: 4 corner addrs x {0,64} pairs
  f4 acc[4];
#pragma unroll
  for (int mm = 0; mm < 4; ++mm) acc[mm] = (f4)0.f;

  const char* Xb = (const char*)Xs;
  const int cbL = lq8 * 2;              // lane channel byte offset within pixel block

#pragma unroll
  for (int k = 0; k < 9; ++k) {
    const int kr = k / 3, kc = k - kr * 3;
    float oy = Soff[wv][lm][2 * k];
    float ox = Soff[wv][lm][2 * k + 1];
    float mk = Soff[wv][lm][18 + k];
    float py = (float)(y + kr - 1) + oy;
    float pxf = (float)(gpx + kc - 1) + ox;
    float fy = floorf(py), fx = floorf(pxf);
    float wy = py - fy, wx = pxf - fx;
    int y0 = (int)fy, x0 = (int)fx;
    int y1 = y0 + 1, x1 = x0 + 1;
    float vy0 = ((unsigned)y0 < 128u) ? 1.f : 0.f;
    float vy1 = ((unsigned)y1 < 128u) ? 1.f : 0.f;
    float vx0 = ((unsigned)x0 < 128u) ? 1.f : 0.f;
    float vx1 = ((unsigned)x1 < 128u) ? 1.f : 0.f;
    float ey = 1.f - wy, ex = 1.f - wx;
    _Float16 w00 = (_Float16)(ey * ex * mk * vy0 * vx0);
    _Float16 w01 = (_Float16)(ey * wx * mk * vy0 * vx1);
    _Float16 w10 = (_Float16)(wy * ex * mk * vy1 * vx0);
    _Float16 w11 = (_Float16)(wy * wx * mk * vy1 * vx1);
    h2 W00 = {w00, w00}, W01 = {w01, w01}, W10 = {w10, w10}, W11 = {w11, w11};
    int y0c = min(max(y0, 0), 127) + 1, y1c = min(max(y1, 0), 127) + 1;
    int x0c = min(max(x0, 0), 127) + 1, x1c = min(max(x1, 0), 127) + 1;
    const void* a00 = (const void*)(Xb + (rb + y0c) * 16640 + x0c * 128 + cbL);
    const void* a01 = (const void*)(Xb + (rb + y0c) * 16640 + x1c * 128 + cbL);
    const void* a10 = (const void*)(Xb + (rb + y1c) * 16640 + x0c * 128 + cbL);
    const void* a11 = (const void*)(Xb + (rb + y1c) * 16640 + x1c * 128 + cbL);
    h8 gv[8];                           // [corner 4][s 2]: gv[2c+s]
    asm volatile(
        "global_load_dwordx4 %0, %8, off\n\t"
        "global_load_dwordx4 %1, %8, off offset:64\n\t"
        "global_load_dwordx4 %2, %9, off\n\t"
        "global_load_dwordx4 %3, %9, off offset:64\n\t"
        "global_load_dwordx4 %4, %10, off\n\t"
        "global_load_dwordx4 %5, %10, off offset:64\n\t"
        "global_load_dwordx4 %6, %11, off\n\t"
        "global_load_dwordx4 %7, %11, off offset:64\n\t"
        "s_waitcnt vmcnt(0)"
        : "=&v"(gv[0]), "=&v"(gv[1]), "=&v"(gv[2]), "=&v"(gv[3]),
          "=&v"(gv[4]), "=&v"(gv[5]), "=&v"(gv[6]), "=&v"(gv[7])
        : "v"(a00), "v"(a01), "v"(a10), "v"(a11)
        : "memory");
#pragma unroll
    for (int s = 0; s < 2; ++s) {
      h8 bv;
#pragma unroll
      for (int j2 = 0; j2 < 4; ++j2) {
        h2 a  = {gv[0 + s][2 * j2], gv[0 + s][2 * j2 + 1]};
        h2 bb = {gv[2 + s][2 * j2], gv[2 + s][2 * j2 + 1]};
        h2 cc = {gv[4 + s][2 * j2], gv[4 + s][2 * j2 + 1]};
        h2 dd = {gv[6 + s][2 * j2], gv[6 + s][2 * j2 + 1]};
        h2 r = a * W00;
        r += bb * W01;
        r += cc * W10;
        r += dd * W11;
        bv[2 * j2] = r[0];
        bv[2 * j2 + 1] = r[1];
      }
      const _Float16* wp = wD + (size_t)(k * 2 + s) * 2048 + L * 8;
      acc[0] = __builtin_amdgcn_mfma_f32_16x16x32_f16(*(const h8*)(wp), bv, acc[0], 0, 0, 0);
      acc[1] = __builtin_amdgcn_mfma_f32_16x16x32_f16(*(const h8*)(wp + 512), bv, acc[1], 0, 0, 0);
      acc[2] = __builtin_amdgcn_mfma_f32_16x16x32_f16(*(const h8*)(wp + 1024), bv, acc[2], 0, 0, 0);
      acc[3] = __builtin_amdgcn_mfma_f32_16x16x32_f16(*(const h8*)(wp + 1536), bv, acc[3], 0, 0, 0);
    }
  }

  // epilogue: bias + lrelu, fp32 NCHW
#pragma unroll
  for (int mt = 0; mt < 4; ++mt)
#pragma unroll
    for (int r = 0; r < 4; ++r) {
      int oc = mt * 16 + lq * 4 + r;
      float v = acc[mt][r] + bd[oc];
      v = (v >= 0.f) ? v : 0.1f * v;
      out[(((b << 6) + oc) << 14) + (y << 7) + gpx] = v;
    }
}

extern "C" void kernel_launch(void* const* d_in, const int* in_sizes, int n_in,
                              void* d_out, int out_size, void* d_ws, size_t ws_size,
                              hipStream_t stream) {
  const float* nbr   = (const float*)d_in[0];
  const float* refp  = (const float*)d_in[1];
  const float* w1    = (const float*)d_in[2];
  const float* b1    = (const float*)d_in[3];
  const float* w2    = (const float*)d_in[4];
  const float* b2    = (const float*)d_in[5];
  const float* w3    = (const float*)d_in[6];
  const float* b3    = (const float*)d_in[7];
  const float* w_off = (const float*)d_in[8];
  const float* b_off = (const float*)d_in[9];
  const float* w_dcn = (const float*)d_in[10];
  const float* b_dcn = (const float*)d_in[11];

  float* outp = (float*)d_out;
  float* feat = outp;                       // 4*64*16384
  float* offp = outp + 4194304;             // 4*18*16384
  float* mskp = outp + 4194304 + 1179648;   // 4*9*16384

  // ws layout: four padded NHWC f16 buffers [4][130][130][64] + f16 weights (~33.4 MiB)
  char* ws = (char*)d_ws;
  const size_t PB = 8652800;                // bytes per padded buffer
  _Float16* X1  = (_Float16*)ws;            // nbr padded (conv1 in + DCN sample src)
  _Float16* X2  = (_Float16*)(ws + PB);     // ref padded
  _Float16* B64 = (_Float16*)(ws + 2 * PB); // conv1 out / conv3 out
  _Float16* C64 = (_Float16*)(ws + 3 * PB); // conv2 out
  char* p = ws + 4 * PB;
  _Float16* wF1 = (_Float16*)p;  p += (size_t)73728 * 2;
  _Float16* wF2 = (_Float16*)p;  p += (size_t)36864 * 2;
  _Float16* wF3 = (_Float16*)p;  p += (size_t)36864 * 2;
  _Float16* wFo = (_Float16*)p;  p += (size_t)18432 * 2;
  _Float16* wFd = (_Float16*)p;

  // 5 dispatches total
  setup_kernel<<<dim3(3098), 256, 0, stream>>>(nbr, refp, w1, w2, w3, w_off, w_dcn,
                                               X1, X2, B64, C64, wF1, wF2, wF3, wFo, wFd);
  conv3x3_lds_kernel<4, true><<<dim3(1024), 256, 0, stream>>>(X1, X2, wF1, b1, B64);
  conv3x3_lds_kernel<2, false><<<dim3(1024), 256, 0, stream>>>(B64, nullptr, wF2, b2, C64);
  conv3x3_lds_kernel<2, false><<<dim3(1024), 256, 0, stream>>>(C64, nullptr, wF3, b3, B64);
  off_dcn_kernel<<<dim3(1024), 256, 0, stream>>>(B64, X1, wFo, b_off, wFd, b_dcn,
                                                 offp, mskp, feat);
}